// Round 1
// baseline (364.234 us; speedup 1.0000x reference)
//
#include <hip/hip_runtime.h>
#include <math.h>

#define DDIM 512
#define NNN  4096
#define KKK  2048
#define MMM  32768          // 8*4096 queries

#define TMQ  128            // queries per block (main)
#define TNC  256            // codes per k-tile (main)
#define BK   64             // d per staging round (main)
#define KSPLIT 4            // grid 1024 -> 3 blocks/CU resident (was 2 -> grid-capped at 2/CU)
#define KHALF (KKK/KSPLIT)  // 512
#define NKT  (KHALF/TNC)    // 2
#define NDR  (DDIM/BK)      // 8
#define TAU  0.25f          // flag margin for exact re-resolve
#define CAPF 4096           // flagged-query capacity

// d_out scratch layout (floats) inside the quantize region [0, 16777216),
// fully overwritten by the final gather:
#define XH_OFF   0                      // x^T bf16 [m][d]: 8388608 floats
#define EH_OFF   8388608                // embed bf16 [k][d]: 524288 floats
#define PART_OFF (EH_OFF + 524288)      // per (q,ks) triple: MMM*KSPLIT*4 = 524288 floats
#define XF_OFF   (PART_OFF + 524288)    // compact fp32 x [slot][d]: CAPF*512
#define KEY_OFF  (XF_OFF + 2097152)     // CAPF u64 keys (byte off %8 == 0)
#define LIST_OFF (KEY_OFF + 8192)       // flagged-query list (ints)
#define CNT_OFF  (LIST_OFF + CAPF)      // atomic counter (int)
#define IDX_OFF  ((size_t)MMM * DDIM)   // output 1: indices as float

typedef short short8v __attribute__((ext_vector_type(8)));
typedef float f32x4   __attribute__((ext_vector_type(4)));

__device__ inline unsigned short f2bf(float f) {          // fp32 -> bf16 RNE
  unsigned u = __float_as_uint(f);
  u = u + 0x7FFFu + ((u >> 16) & 1u);
  return (unsigned short)(u >> 16);
}

// async global->LDS, 16B per lane; LDS dest = uniform base + lane*16
__device__ inline void gl_lds16(const short* g, short* l) {
  __builtin_amdgcn_global_load_lds(
      (const __attribute__((address_space(1))) unsigned int*)g,
      (__attribute__((address_space(3))) unsigned int*)l, 16, 0, 0);
}

__device__ inline unsigned mono(float f) {   // monotone float -> uint
  unsigned u = __float_as_uint(f);
  return (u & 0x80000000u) ? ~u : (u | 0x80000000u);
}

// XOR-swizzled frag-read short-index into a [rows][64-short] tile:
// physical 16B-quad = (dk>>3) ^ (row&7). Kills the 16-way conflicts of the
// linear layout (row stride 128 B == 0 mod 32 banks); 16 lanes now spread
// over 8 bank-quads = 2-way (free, m136).
__device__ inline int fswz(int row, int dk) {
  return row*64 + ((((dk >> 3) ^ (row & 7)) << 3));
}

// ---- embed -> bf16 plane + halfe2 + init counter/keys ----------------------
__global__ void conv_e(const float* __restrict__ embed, float* __restrict__ halfe2,
                       float* __restrict__ out) {
  const int gid = blockIdx.x * 256 + threadIdx.x;
  if (gid == 0) *(int*)&out[CNT_OFF] = 0;
  if (gid < CAPF) ((unsigned long long*)&out[KEY_OFF])[gid] = ~0ull;
  const int row  = blockIdx.x * 4 + (threadIdx.x >> 6);
  const int lane = threadIdx.x & 63;
  const float* e = embed + (size_t)row * DDIM;
  short* eh = (short*)&out[EH_OFF];
  const float4 v0 = *(const float4*)&e[lane*8];
  const float4 v1 = *(const float4*)&e[lane*8 + 4];
  const float vv[8] = {v0.x,v0.y,v0.z,v0.w,v1.x,v1.y,v1.z,v1.w};
  float s = 0.f;
  short8v p;
  #pragma unroll
  for (int i = 0; i < 8; ++i) { s = fmaf(vv[i], vv[i], s); p[i] = (short)f2bf(vv[i]); }
  *(short8v*)&eh[(size_t)row * DDIM + lane*8] = p;
  #pragma unroll
  for (int off = 32; off >= 1; off >>= 1) s += __shfl_xor(s, off, 64);
  if (lane == 0) halfe2[row] = 0.5f * s;
}

// ---- x [b][d][n] -> transposed bf16 plane xh[m][d] (m = b*4096+n) ----------
__global__ __launch_bounds__(256)
void conv_x(const float* __restrict__ x, float* __restrict__ out) {
  __shared__ float xt[64][65];          // +1 pad: conflict-free column reads
  const int t  = threadIdx.x;
  const int nt = blockIdx.x & 63, dt = (blockIdx.x >> 6) & 7, b = blockIdx.x >> 9;
  const int n0 = nt * 64, d0 = dt * 64;
  const float* xb = x + ((size_t)b * DDIM + d0) * NNN + n0;
  #pragma unroll
  for (int i = 0; i < 4; ++i) {
    const int fid = t + 256*i;
    const int dl = fid >> 4, n4 = (fid & 15) * 4;
    const float4 v = *(const float4*)&xb[(size_t)dl * NNN + n4];
    xt[dl][n4+0] = v.x; xt[dl][n4+1] = v.y; xt[dl][n4+2] = v.z; xt[dl][n4+3] = v.w;
  }
  __syncthreads();
  short* xh = (short*)&out[XH_OFF];
  const int m0 = b * NNN + n0;
  #pragma unroll
  for (int i = 0; i < 2; ++i) {
    const int id = t + 256*i;
    const int m = id >> 3, ch = (id & 7) * 8;
    short8v p;
    #pragma unroll
    for (int j = 0; j < 8; ++j) p[j] = (short)f2bf(xt[ch + j][m]);
    *(short8v*)&xh[(size_t)(m0 + m) * DDIM + d0 + ch] = p;
  }
}

// ---- main: pure bf16 MFMA GEMM + deferred fused argmin ---------------------
// score[q][k] = 0.5*||e_k||^2 - <x_q, e_k>
__global__ __launch_bounds__(256, 2)
void vq_main(const float* __restrict__ halfe2, float* __restrict__ out) {
  __shared__ __align__(16) short lds[(TMQ + TNC) * BK];   // 48 KB -> 3 blocks/CU
  short* xs = lds;              // [128 rows][64 d], XOR-swizzled quads
  short* es = lds + TMQ*BK;     // [256 rows][64 d], XOR-swizzled quads
  const short* xh = (const short*)&out[XH_OFF];
  const short* eh = (const short*)&out[EH_OFF];

  const int t  = threadIdx.x;
  const int mb = blockIdx.x >> 2, ks = blockIdx.x & 3;
  const int q0 = mb * TMQ;
  const int kbase = ks * KHALF;
  const int w = t >> 6, lane = t & 63;
  const int mw = (w >> 1) * 64, nw = (w & 1) * 128;   // wave 64x128 sub-tile
  const int l15 = lane & 15, lg = lane >> 4;
  const int c0 = w * 12;
  const int lrow = lane >> 3;                          // staging row within chunk
  const int scol = (((lane & 7) ^ lrow) << 3);         // swizzled source quad

  // deferred per-lane running (best, idx, 2nd-best) for 16 queries/lane
  float rv1[16], rv2[16]; int ri1[16];
  #pragma unroll
  for (int i = 0; i < 16; ++i) { rv1[i] = INFINITY; rv2[i] = INFINITY; ri1[i] = 0x7FFFFFFF; }

  for (int kt = 0; kt < NKT; ++kt) {
    const int kb = kbase + kt * TNC;
    f32x4 acc[4][8];
    #pragma unroll
    for (int mi = 0; mi < 4; ++mi)
      #pragma unroll
      for (int ni = 0; ni < 8; ++ni) acc[mi][ni] = (f32x4){0.f,0.f,0.f,0.f};

    for (int dr = 0; dr < NDR; ++dr) {
      const int d0 = dr * BK;
      __syncthreads();
      // stage 48 KB via global_load_lds; swizzle folded into source column
      #pragma unroll
      for (int j = 0; j < 12; ++j) {
        const int c = c0 + j;
        if (c < 16) {
          gl_lds16(xh + (size_t)(q0 + c*8 + lrow) * DDIM + d0 + scol, &lds[c * 512]);
        } else {
          gl_lds16(eh + (size_t)(kb + (c-16)*8 + lrow) * DDIM + d0 + scol, &lds[c * 512]);
        }
      }
      __syncthreads();
      #pragma unroll
      for (int kk = 0; kk < 2; ++kk) {
        const int dk = kk*32 + lg*8;
        short8v bfr[8];
        #pragma unroll
        for (int ni = 0; ni < 8; ++ni)
          bfr[ni] = *(const short8v*)&es[fswz(nw + ni*16 + l15, dk)];
        #pragma unroll
        for (int mi = 0; mi < 4; ++mi) {
          const short8v a = *(const short8v*)&xs[fswz(mw + mi*16 + l15, dk)];
          #pragma unroll
          for (int ni = 0; ni < 8; ++ni)
            acc[mi][ni] = __builtin_amdgcn_mfma_f32_16x16x32_bf16(a, bfr[ni], acc[mi][ni], 0,0,0);
        }
      }
    }

    // per-k-tile: per-lane tournament only (no cross-lane traffic);
    // candidate indices strictly ascend -> strict < keeps first index
    float he[8];
    #pragma unroll
    for (int ni = 0; ni < 8; ++ni) he[ni] = halfe2[kb + nw + ni*16 + l15];
    #pragma unroll
    for (int mi = 0; mi < 4; ++mi) {
      #pragma unroll
      for (int r = 0; r < 4; ++r) {
        const int e_ = mi*4 + r;
        #pragma unroll
        for (int ni = 0; ni < 8; ++ni) {
          const float sc = he[ni] - acc[mi][ni][r];
          if (sc < rv1[e_]) { rv2[e_] = rv1[e_]; rv1[e_] = sc; ri1[e_] = kb + nw + ni*16 + l15; }
          else rv2[e_] = fminf(rv2[e_], sc);
        }
      }
    }
  }

  // once: cross-lane merge over the 16 code-columns (within each 16-lane group)
  #pragma unroll
  for (int e_ = 0; e_ < 16; ++e_) {
    float v1 = rv1[e_], v2 = rv2[e_]; int i1 = ri1[e_];
    #pragma unroll
    for (int off = 1; off < 16; off <<= 1) {
      const float ov1 = __shfl_xor(v1, off, 64);
      const int   oi1 = __shfl_xor(i1, off, 64);
      const float ov2 = __shfl_xor(v2, off, 64);
      if (ov1 < v1 || (ov1 == v1 && oi1 < i1)) { v2 = fminf(v1, ov2); v1 = ov1; i1 = oi1; }
      else v2 = fminf(v2, ov1);
    }
    rv1[e_] = v1; rv2[e_] = v2; ri1[e_] = i1;
  }

  // merge the two code-half waves (w&1) per query via LDS; store partial triple
  __syncthreads();
  float* mbuf = (float*)lds;   // [128 q][2 halves][3]
  if (l15 == 0) {
    #pragma unroll
    for (int mi = 0; mi < 4; ++mi)
      #pragma unroll
      for (int r = 0; r < 4; ++r) {
        const int ql = mw + mi*16 + lg*4 + r;
        const int slot = (ql*2 + (w & 1))*3;
        const int e_ = mi*4 + r;
        mbuf[slot+0] = rv1[e_];
        mbuf[slot+1] = __int_as_float(ri1[e_]);
        mbuf[slot+2] = rv2[e_];
      }
  }
  __syncthreads();
  if (t < TMQ) {
    const float a1 = mbuf[t*6+0]; const int ai = __float_as_int(mbuf[t*6+1]); const float a2 = mbuf[t*6+2];
    const float b1 = mbuf[t*6+3]; const int bi = __float_as_int(mbuf[t*6+4]); const float b2 = mbuf[t*6+5];
    float v1, v2; int i1;
    if (b1 < a1 || (b1 == a1 && bi < ai)) { v1 = b1; i1 = bi; v2 = fminf(a1, b2); }
    else                                  { v1 = a1; i1 = ai; v2 = fminf(a2, b1); }
    f32x4 st = {v1, (float)i1, v2, 0.f};
    *(f32x4*)&out[PART_OFF + ((size_t)(q0 + t)*KSPLIT + ks)*4] = st;
  }
}

// ---- merge K-split partials; write index; flag ambiguous queries -----------
__global__ void vq_merge(float* __restrict__ out) {
  const int q = blockIdx.x * 256 + threadIdx.x;
  float v1, v2; int i1;
  {
    const f32x4 p = *(const f32x4*)&out[PART_OFF + (size_t)q*(KSPLIT*4)];
    v1 = p[0]; i1 = (int)p[1]; v2 = p[2];
  }
  #pragma unroll
  for (int s = 1; s < KSPLIT; ++s) {
    const f32x4 p = *(const f32x4*)&out[PART_OFF + (size_t)q*(KSPLIT*4) + s*4];
    const float b1 = p[0]; const int bi = (int)p[1]; const float b2 = p[2];
    // splits cover disjoint ascending code ranges; sequential merge keeps
    // the exact global (best, idx, 2nd-best): if b1 wins, 2nd = min(old best, b2);
    // else 2nd = min(old 2nd, b1) (b2 >= b1 >= v1 is irrelevant).
    if (b1 < v1 || (b1 == v1 && bi < i1)) { v2 = fminf(v1, b2); v1 = b1; i1 = bi; }
    else v2 = fminf(v2, b1);
  }
  out[IDX_OFF + q] = (float)i1;
  if (v2 - v1 < TAU) {
    const int pos = atomicAdd((int*)&out[CNT_OFF], 1);
    if (pos < CAPF) ((int*)&out[LIST_OFF])[pos] = q;
  }
}

// ---- prep: compact flagged x rows into fp32 plane XF[slot][d] --------------
// reads scattered (inherent to x layout, L3-resident); writes coalesced 256B/wave
__global__ __launch_bounds__(256)
void vq_prep(const float* __restrict__ x, float* __restrict__ out) {
  const int nf0 = *(const int*)&out[CNT_OFF];
  const int nf  = nf0 < CAPF ? nf0 : CAPF;
  const int* list = (const int*)&out[LIST_OFF];
  float* XF = &out[XF_OFF];
  const int wid  = (blockIdx.x * 256 + threadIdx.x) >> 6;   // 1024 waves
  const int lane = threadIdx.x & 63;
  for (int s = wid; s < nf; s += 1024) {
    const int q = list[s];
    const int b = q >> 12, n = q & (NNN - 1);
    const float* xb = x + (size_t)b * DDIM * NNN + n;
    #pragma unroll
    for (int j = 0; j < 8; ++j) {
      const int d = lane + 64*j;
      XF[(size_t)s * DDIM + d] = xb[(size_t)d * NNN];
    }
  }
}

// ---- refine: exact fp32 microtile GEMM over flagged slots ------------------
// block = 64 slots x 128 codes; 4x8 register microtile;
// deterministic cross-block merge via monotone-key atomicMin.
__global__ __launch_bounds__(256, 2)
void vq_refine(const float* __restrict__ embed, const float* __restrict__ halfe2,
               float* __restrict__ out) {
  const int nf0 = *(const int*)&out[CNT_OFF];
  const int nf  = nf0 < CAPF ? nf0 : CAPF;
  const int s0  = blockIdx.y * 64;
  if (s0 >= nf) return;
  __shared__ float xs[32][68];   // stride 68: float4-aligned, <=4-way stage writes
  __shared__ float es[32][132];
  const int t = threadIdx.x, tx = t & 15, ty = t >> 4;
  const int kb = blockIdx.x * 128;
  const float* XF = &out[XF_OFF];
  unsigned long long* keys = (unsigned long long*)&out[KEY_OFF];

  float acc[4][8];
  #pragma unroll
  for (int i = 0; i < 4; ++i)
    #pragma unroll
    for (int j = 0; j < 8; ++j) acc[i][j] = 0.f;

  for (int dc = 0; dc < 16; ++dc) {
    __syncthreads();
    #pragma unroll
    for (int i = 0; i < 2; ++i) {        // xs[d][m] <- XF[s0+m][.] row float4 reads
      const int l = t + 256*i;           // 512 float4
      const int m = l >> 3, f = l & 7;
      const float4 v = *(const float4*)&XF[(size_t)(s0 + m) * DDIM + dc*32 + 4*f];
      xs[4*f+0][m] = v.x; xs[4*f+1][m] = v.y; xs[4*f+2][m] = v.z; xs[4*f+3][m] = v.w;
    }
    #pragma unroll
    for (int i = 0; i < 4; ++i) {        // es[d][k] <- embed rows (float4)
      const int l = t + 256*i;
      const int k = l >> 3, f = l & 7;
      const float4 v = *(const float4*)&embed[(size_t)(kb + k)*DDIM + dc*32 + 4*f];
      es[4*f+0][k] = v.x; es[4*f+1][k] = v.y; es[4*f+2][k] = v.z; es[4*f+3][k] = v.w;
    }
    __syncthreads();
    #pragma unroll
    for (int d = 0; d < 32; ++d) {       // sequential d: deterministic sum order
      const float4 a4 = *(const float4*)&xs[d][ty*4];
      const float4 b0 = *(const float4*)&es[d][tx*4];
      const float4 b1 = *(const float4*)&es[d][64 + tx*4];
      const float a[4]  = {a4.x, a4.y, a4.z, a4.w};
      const float bb[8] = {b0.x, b0.y, b0.z, b0.w, b1.x, b1.y, b1.z, b1.w};
      #pragma unroll
      for (int i = 0; i < 4; ++i)
        #pragma unroll
        for (int j = 0; j < 8; ++j)
          acc[i][j] = fmaf(a[i], bb[j], acc[i][j]);
    }
  }

  const int kb0 = kb + tx*4, kb1 = kb + 64 + tx*4;
  const float4 h0 = *(const float4*)&halfe2[kb0];
  const float4 h1 = *(const float4*)&halfe2[kb1];
  const float hh[8] = {h0.x, h0.y, h0.z, h0.w, h1.x, h1.y, h1.z, h1.w};
  #pragma unroll
  for (int i = 0; i < 4; ++i) {
    float v = hh[0] - acc[i][0];
    int  vi = kb0;
    #pragma unroll
    for (int j = 1; j < 8; ++j) {
      const float w  = hh[j] - acc[i][j];
      const int   wk = (j < 4) ? (kb0 + j) : (kb1 + j - 4);
      if (w < v) { v = w; vi = wk; }     // ascending codes: strict < keeps first
    }
    #pragma unroll
    for (int off = 1; off < 16; off <<= 1) {
      const float ov = __shfl_xor(v, off, 64);
      const int   oi = __shfl_xor(vi, off, 64);
      if (ov < v || (ov == v && oi < vi)) { v = ov; vi = oi; }
    }
    if (tx == 0) {
      const unsigned long long key =
          ((unsigned long long)mono(v) << 32) | (unsigned)vi;
      atomicMin(&keys[s0 + ty*4 + i], key);
    }
  }
}

// ---- apply: decode refined keys back into IDX ------------------------------
__global__ void vq_apply(float* __restrict__ out) {
  const int slot = blockIdx.x * 256 + threadIdx.x;
  const int nf0 = *(const int*)&out[CNT_OFF];
  const int nf  = nf0 < CAPF ? nf0 : CAPF;
  if (slot >= nf) return;
  const int q = ((const int*)&out[LIST_OFF])[slot];
  const unsigned long long k = ((const unsigned long long*)&out[KEY_OFF])[slot];
  if (k != ~0ull) out[IDX_OFF + q] = (float)(unsigned)(k & 0xFFFFFFFFull);
}

// ---- gather quantize rows, float4 stores (overwrites all d_out scratch) ----
__global__ __launch_bounds__(256)
void vq_gather(const float* __restrict__ embed, float* __restrict__ out) {
  __shared__ int idx_s[128];
  const int t  = threadIdx.x;
  const int q0 = blockIdx.x * 128;
  const int b  = q0 >> 12, n0 = q0 & (NNN-1);
  if (t < 128) idx_s[t] = (int)out[IDX_OFF + q0 + t];
  __syncthreads();
  float* qb = out + (size_t)b * DDIM * NNN + n0;
  for (int j = 0; j < 64; ++j) {
    const int id = t + 256*j;
    const int d = id >> 5, n4 = (id & 31) * 4;
    float4 v;
    v.x = embed[(size_t)idx_s[n4+0]*DDIM + d];
    v.y = embed[(size_t)idx_s[n4+1]*DDIM + d];
    v.z = embed[(size_t)idx_s[n4+2]*DDIM + d];
    v.w = embed[(size_t)idx_s[n4+3]*DDIM + d];
    *(float4*)&qb[(size_t)d * NNN + n4] = v;
  }
}

extern "C" void kernel_launch(void* const* d_in, const int* in_sizes, int n_in,
                              void* d_out, int out_size, void* d_ws, size_t ws_size,
                              hipStream_t stream) {
  const float* x     = (const float*)d_in[0];   // [8, 512, 4096] fp32
  const float* embed = (const float*)d_in[1];   // [2048, 512] fp32
  float* out    = (float*)d_out;
  float* halfe2 = (float*)d_ws;                 // 8 KB scratch

  hipLaunchKernelGGL(conv_e,   dim3(KKK/4),   dim3(256), 0, stream, embed, halfe2, out);
  hipLaunchKernelGGL(conv_x,   dim3(4096),    dim3(256), 0, stream, x, out);
  hipLaunchKernelGGL(vq_main,  dim3((MMM/TMQ)*KSPLIT), dim3(256), 0, stream, halfe2, out);
  hipLaunchKernelGGL(vq_merge, dim3(MMM/256), dim3(256), 0, stream, out);
  hipLaunchKernelGGL(vq_prep,  dim3(256),     dim3(256), 0, stream, x, out);
  hipLaunchKernelGGL(vq_refine,dim3(16, CAPF/64), dim3(256), 0, stream, embed, halfe2, out);
  hipLaunchKernelGGL(vq_apply, dim3(CAPF/256),dim3(256), 0, stream, out);
  hipLaunchKernelGGL(vq_gather,dim3(MMM/128), dim3(256), 0, stream, embed, out);
}

// Round 2
// 327.626 us; speedup vs baseline: 1.1117x; 1.1117x over previous
//
#include <hip/hip_runtime.h>
#include <math.h>

#define DDIM 512
#define NNN  4096
#define KKK  2048
#define MMM  32768          // 8*4096 queries

#define TMQ  128            // queries per block (main)
#define TNC  256            // codes per k-tile (main)
#define BK   32             // d per staging round (main) -- halved for double-buffer
#define KSPLIT 2            // reverted: occupancy is register-bound (acc=128 AGPR), not grid-bound
#define KHALF (KKK/KSPLIT)  // 1024
#define NKT  (KHALF/TNC)    // 4
#define NDR  (DDIM/BK)      // 16
#define TOTR (NKT*NDR)      // 64 pipelined rounds per block
#define BUFS ((TMQ+TNC)*BK) // 12288 shorts = 24 KB per buffer
#define TAU  0.25f          // flag margin for exact re-resolve
#define CAPF 4096           // flagged-query capacity

// d_out scratch layout (floats) inside the quantize region [0, 16777216),
// fully overwritten by the final gather:
#define XH_OFF   0                      // x^T bf16 [m][d]: 8388608 floats
#define EH_OFF   8388608                // embed bf16 [k][d]: 524288 floats
#define PART_OFF (EH_OFF + 524288)      // per (q,ks) triple: MMM*KSPLIT*4 floats
#define XF_OFF   (PART_OFF + MMM*KSPLIT*4)  // compact fp32 x [slot][d]: CAPF*512
#define KEY_OFF  (XF_OFF + 2097152)     // CAPF u64 keys (byte off %8 == 0)
#define LIST_OFF (KEY_OFF + 8192)       // flagged-query list (ints)
#define CNT_OFF  (LIST_OFF + CAPF)      // atomic counter (int)
#define IDX_OFF  ((size_t)MMM * DDIM)   // output 1: indices as float

typedef short short8v __attribute__((ext_vector_type(8)));
typedef float f32x4   __attribute__((ext_vector_type(4)));

__device__ inline unsigned short f2bf(float f) {          // fp32 -> bf16 RNE
  unsigned u = __float_as_uint(f);
  u = u + 0x7FFFu + ((u >> 16) & 1u);
  return (unsigned short)(u >> 16);
}

// async global->LDS, 16B per lane; LDS dest = uniform base + lane*16
__device__ inline void gl_lds16(const short* g, short* l) {
  __builtin_amdgcn_global_load_lds(
      (const __attribute__((address_space(1))) unsigned int*)g,
      (__attribute__((address_space(3))) unsigned int*)l, 16, 0, 0);
}

__device__ inline unsigned mono(float f) {   // monotone float -> uint
  unsigned u = __float_as_uint(f);
  return (u & 0x80000000u) ? ~u : (u | 0x80000000u);
}

// ---- embed -> bf16 plane + halfe2 + init counter/keys ----------------------
__global__ void conv_e(const float* __restrict__ embed, float* __restrict__ halfe2,
                       float* __restrict__ out) {
  const int gid = blockIdx.x * 256 + threadIdx.x;
  if (gid == 0) *(int*)&out[CNT_OFF] = 0;
  if (gid < CAPF) ((unsigned long long*)&out[KEY_OFF])[gid] = ~0ull;
  const int row  = blockIdx.x * 4 + (threadIdx.x >> 6);
  const int lane = threadIdx.x & 63;
  const float* e = embed + (size_t)row * DDIM;
  short* eh = (short*)&out[EH_OFF];
  const float4 v0 = *(const float4*)&e[lane*8];
  const float4 v1 = *(const float4*)&e[lane*8 + 4];
  const float vv[8] = {v0.x,v0.y,v0.z,v0.w,v1.x,v1.y,v1.z,v1.w};
  float s = 0.f;
  short8v p;
  #pragma unroll
  for (int i = 0; i < 8; ++i) { s = fmaf(vv[i], vv[i], s); p[i] = (short)f2bf(vv[i]); }
  *(short8v*)&eh[(size_t)row * DDIM + lane*8] = p;
  #pragma unroll
  for (int off = 32; off >= 1; off >>= 1) s += __shfl_xor(s, off, 64);
  if (lane == 0) halfe2[row] = 0.5f * s;
}

// ---- x [b][d][n] -> transposed bf16 plane xh[m][d] (m = b*4096+n) ----------
__global__ __launch_bounds__(256)
void conv_x(const float* __restrict__ x, float* __restrict__ out) {
  __shared__ float xt[64][65];          // +1 pad: conflict-free column reads
  const int t  = threadIdx.x;
  const int nt = blockIdx.x & 63, dt = (blockIdx.x >> 6) & 7, b = blockIdx.x >> 9;
  const int n0 = nt * 64, d0 = dt * 64;
  const float* xb = x + ((size_t)b * DDIM + d0) * NNN + n0;
  #pragma unroll
  for (int i = 0; i < 4; ++i) {
    const int fid = t + 256*i;
    const int dl = fid >> 4, n4 = (fid & 15) * 4;
    const float4 v = *(const float4*)&xb[(size_t)dl * NNN + n4];
    xt[dl][n4+0] = v.x; xt[dl][n4+1] = v.y; xt[dl][n4+2] = v.z; xt[dl][n4+3] = v.w;
  }
  __syncthreads();
  short* xh = (short*)&out[XH_OFF];
  const int m0 = b * NNN + n0;
  #pragma unroll
  for (int i = 0; i < 2; ++i) {
    const int id = t + 256*i;
    const int m = id >> 3, ch = (id & 7) * 8;
    short8v p;
    #pragma unroll
    for (int j = 0; j < 8; ++j) p[j] = (short)f2bf(xt[ch + j][m]);
    *(short8v*)&xh[(size_t)(m0 + m) * DDIM + d0 + ch] = p;
  }
}

// ---- main: double-buffered pipelined bf16 MFMA GEMM + deferred argmin ------
// score[q][k] = 0.5*||e_k||^2 - <x_q, e_k>
// T3-minimum 2-phase: STAGE(next) || compute(cur); one vmcnt(0)+s_barrier/round.
// LDS rows are 64B (4x16B quads); swizzle physquad = (q + (row>>1)) & 3 makes
// every 8-lane group of the frag ds_read_b128 cover all 8 bank-slots once
// (conflict-free); inverse permutation folded into the per-lane GLOBAL source
// address so the linear gl_lds dest constraint holds (rule #21).
__global__ __launch_bounds__(256, 2)
void vq_main(const float* __restrict__ halfe2, float* __restrict__ out) {
  __shared__ __align__(16) short lds[2 * BUFS];   // 48 KB total (2 x 24 KB)
  const short* xh = (const short*)&out[XH_OFF];
  const short* eh = (const short*)&out[EH_OFF];

  const int t  = threadIdx.x;
  const int mb = blockIdx.x >> 1, ks = blockIdx.x & 1;
  const int q0 = mb * TMQ;
  const int kbase = ks * KHALF;
  const int w = t >> 6, lane = t & 63;
  const int mw = (w >> 1) * 64, nw = (w & 1) * 128;   // wave 64x128 sub-tile
  const int l15 = lane & 15, lg = lane >> 4;
  const int c0 = w * 6;                                // 6 1-KB chunks per wave
  const int lrow = lane >> 2;                          // row within 16-row chunk
  // physical slot (lane&3) holds logical quad (p - (row>>1)) & 3:
  const int scol = ((((lane & 3) - ((lane >> 3) & 3)) & 3) << 3);

  // deferred per-lane running (best, idx, 2nd-best) for 16 queries/lane
  float rv1[16], rv2[16]; int ri1[16];
  #pragma unroll
  for (int i = 0; i < 16; ++i) { rv1[i] = INFINITY; rv2[i] = INFINITY; ri1[i] = 0x7FFFFFFF; }

  // stage round R (24 KB: 128 q-rows + 256 e-rows x 32 d) into buf[R&1]
  auto STAGE = [&](int R) {
    const int kt = R >> 4, dr = R & 15;
    const int kb_ = kbase + kt * TNC;
    const int d0 = dr * BK;
    short* buf = lds + (R & 1) * BUFS;
    #pragma unroll
    for (int j = 0; j < 6; ++j) {
      const int c = c0 + j;
      const short* src = (c < 8)
        ? xh + (size_t)(q0 + c*16 + lrow) * DDIM + d0 + scol
        : eh + (size_t)(kb_ + (c-8)*16 + lrow) * DDIM + d0 + scol;
      gl_lds16(src, buf + c * 512);
    }
  };

  // prologue: fill buf0, drain, sync
  STAGE(0);
  asm volatile("s_waitcnt vmcnt(0)" ::: "memory");
  __builtin_amdgcn_s_barrier();

  for (int kt = 0; kt < NKT; ++kt) {
    const int kb = kbase + kt * TNC;
    f32x4 acc[4][8];
    #pragma unroll
    for (int mi = 0; mi < 4; ++mi)
      #pragma unroll
      for (int ni = 0; ni < 8; ++ni) acc[mi][ni] = (f32x4){0.f,0.f,0.f,0.f};

    #pragma unroll 2
    for (int dr = 0; dr < NDR; ++dr) {
      const int R = kt * NDR + dr;
      const short* cur = lds + (R & 1) * BUFS;
      if (R + 1 < TOTR) STAGE(R + 1);          // prefetch flies under the MFMAs
      const short* xs = cur;
      const short* es = cur + TMQ * BK;
      short8v bfr[8];
      #pragma unroll
      for (int ni = 0; ni < 8; ++ni) {
        const int row = nw + ni*16 + l15;
        bfr[ni] = *(const short8v*)&es[row*32 + (((lg + (row >> 1)) & 3) << 3)];
      }
      #pragma unroll
      for (int mi = 0; mi < 4; ++mi) {
        const int row = mw + mi*16 + l15;
        const short8v a = *(const short8v*)&xs[row*32 + (((lg + (row >> 1)) & 3) << 3)];
        #pragma unroll
        for (int ni = 0; ni < 8; ++ni)
          acc[mi][ni] = __builtin_amdgcn_mfma_f32_16x16x32_bf16(a, bfr[ni], acc[mi][ni], 0,0,0);
      }
      // drain this round's prefetch (latency already covered by compute), sync
      asm volatile("s_waitcnt vmcnt(0)" ::: "memory");
      __builtin_amdgcn_s_barrier();
    }

    // per-k-tile: per-lane tournament only (no cross-lane traffic);
    // candidate indices strictly ascend -> strict < keeps first index
    float he[8];
    #pragma unroll
    for (int ni = 0; ni < 8; ++ni) he[ni] = halfe2[kb + nw + ni*16 + l15];
    #pragma unroll
    for (int mi = 0; mi < 4; ++mi) {
      #pragma unroll
      for (int r = 0; r < 4; ++r) {
        const int e_ = mi*4 + r;
        #pragma unroll
        for (int ni = 0; ni < 8; ++ni) {
          const float sc = he[ni] - acc[mi][ni][r];
          if (sc < rv1[e_]) { rv2[e_] = rv1[e_]; rv1[e_] = sc; ri1[e_] = kb + nw + ni*16 + l15; }
          else rv2[e_] = fminf(rv2[e_], sc);
        }
      }
    }
  }

  // once: cross-lane merge over the 16 code-columns (within each 16-lane group)
  #pragma unroll
  for (int e_ = 0; e_ < 16; ++e_) {
    float v1 = rv1[e_], v2 = rv2[e_]; int i1 = ri1[e_];
    #pragma unroll
    for (int off = 1; off < 16; off <<= 1) {
      const float ov1 = __shfl_xor(v1, off, 64);
      const int   oi1 = __shfl_xor(i1, off, 64);
      const float ov2 = __shfl_xor(v2, off, 64);
      if (ov1 < v1 || (ov1 == v1 && oi1 < i1)) { v2 = fminf(v1, ov2); v1 = ov1; i1 = oi1; }
      else v2 = fminf(v2, ov1);
    }
    rv1[e_] = v1; rv2[e_] = v2; ri1[e_] = i1;
  }

  // merge the two code-half waves (w&1) per query via LDS; store partial triple
  __syncthreads();
  float* mbuf = (float*)lds;   // [128 q][2 halves][3]
  if (l15 == 0) {
    #pragma unroll
    for (int mi = 0; mi < 4; ++mi)
      #pragma unroll
      for (int r = 0; r < 4; ++r) {
        const int ql = mw + mi*16 + lg*4 + r;
        const int slot = (ql*2 + (w & 1))*3;
        const int e_ = mi*4 + r;
        mbuf[slot+0] = rv1[e_];
        mbuf[slot+1] = __int_as_float(ri1[e_]);
        mbuf[slot+2] = rv2[e_];
      }
  }
  __syncthreads();
  if (t < TMQ) {
    const float a1 = mbuf[t*6+0]; const int ai = __float_as_int(mbuf[t*6+1]); const float a2 = mbuf[t*6+2];
    const float b1 = mbuf[t*6+3]; const int bi = __float_as_int(mbuf[t*6+4]); const float b2 = mbuf[t*6+5];
    float v1, v2; int i1;
    if (b1 < a1 || (b1 == a1 && bi < ai)) { v1 = b1; i1 = bi; v2 = fminf(a1, b2); }
    else                                  { v1 = a1; i1 = ai; v2 = fminf(a2, b1); }
    f32x4 st = {v1, (float)i1, v2, 0.f};
    *(f32x4*)&out[PART_OFF + ((size_t)(q0 + t)*KSPLIT + ks)*4] = st;
  }
}

// ---- merge K-split partials; write index; flag ambiguous queries -----------
__global__ void vq_merge(float* __restrict__ out) {
  const int q = blockIdx.x * 256 + threadIdx.x;
  float v1, v2; int i1;
  {
    const f32x4 p = *(const f32x4*)&out[PART_OFF + (size_t)q*(KSPLIT*4)];
    v1 = p[0]; i1 = (int)p[1]; v2 = p[2];
  }
  #pragma unroll
  for (int s = 1; s < KSPLIT; ++s) {
    const f32x4 p = *(const f32x4*)&out[PART_OFF + (size_t)q*(KSPLIT*4) + s*4];
    const float b1 = p[0]; const int bi = (int)p[1]; const float b2 = p[2];
    // splits cover disjoint ascending code ranges; sequential merge keeps
    // the exact global (best, idx, 2nd-best).
    if (b1 < v1 || (b1 == v1 && bi < i1)) { v2 = fminf(v1, b2); v1 = b1; i1 = bi; }
    else v2 = fminf(v2, b1);
  }
  out[IDX_OFF + q] = (float)i1;
  if (v2 - v1 < TAU) {
    const int pos = atomicAdd((int*)&out[CNT_OFF], 1);
    if (pos < CAPF) ((int*)&out[LIST_OFF])[pos] = q;
  }
}

// ---- prep: compact flagged x rows into fp32 plane XF[slot][d] --------------
// reads scattered (inherent to x layout, L3-resident); writes coalesced 256B/wave
__global__ __launch_bounds__(256)
void vq_prep(const float* __restrict__ x, float* __restrict__ out) {
  const int nf0 = *(const int*)&out[CNT_OFF];
  const int nf  = nf0 < CAPF ? nf0 : CAPF;
  const int* list = (const int*)&out[LIST_OFF];
  float* XF = &out[XF_OFF];
  const int wid  = (blockIdx.x * 256 + threadIdx.x) >> 6;   // 1024 waves
  const int lane = threadIdx.x & 63;
  for (int s = wid; s < nf; s += 1024) {
    const int q = list[s];
    const int b = q >> 12, n = q & (NNN - 1);
    const float* xb = x + (size_t)b * DDIM * NNN + n;
    #pragma unroll
    for (int j = 0; j < 8; ++j) {
      const int d = lane + 64*j;
      XF[(size_t)s * DDIM + d] = xb[(size_t)d * NNN];
    }
  }
}

// ---- refine: exact fp32 microtile GEMM over flagged slots ------------------
// block = 64 slots x 128 codes; 4x8 register microtile;
// deterministic cross-block merge via monotone-key atomicMin.
__global__ __launch_bounds__(256, 2)
void vq_refine(const float* __restrict__ embed, const float* __restrict__ halfe2,
               float* __restrict__ out) {
  const int nf0 = *(const int*)&out[CNT_OFF];
  const int nf  = nf0 < CAPF ? nf0 : CAPF;
  const int s0  = blockIdx.y * 64;
  if (s0 >= nf) return;
  __shared__ float xs[32][68];   // stride 68: float4-aligned, <=4-way stage writes
  __shared__ float es[32][132];
  const int t = threadIdx.x, tx = t & 15, ty = t >> 4;
  const int kb = blockIdx.x * 128;
  const float* XF = &out[XF_OFF];
  unsigned long long* keys = (unsigned long long*)&out[KEY_OFF];

  float acc[4][8];
  #pragma unroll
  for (int i = 0; i < 4; ++i)
    #pragma unroll
    for (int j = 0; j < 8; ++j) acc[i][j] = 0.f;

  for (int dc = 0; dc < 16; ++dc) {
    __syncthreads();
    #pragma unroll
    for (int i = 0; i < 2; ++i) {        // xs[d][m] <- XF[s0+m][.] row float4 reads
      const int l = t + 256*i;           // 512 float4
      const int m = l >> 3, f = l & 7;
      const float4 v = *(const float4*)&XF[(size_t)(s0 + m) * DDIM + dc*32 + 4*f];
      xs[4*f+0][m] = v.x; xs[4*f+1][m] = v.y; xs[4*f+2][m] = v.z; xs[4*f+3][m] = v.w;
    }
    #pragma unroll
    for (int i = 0; i < 4; ++i) {        // es[d][k] <- embed rows (float4)
      const int l = t + 256*i;
      const int k = l >> 3, f = l & 7;
      const float4 v = *(const float4*)&embed[(size_t)(kb + k)*DDIM + dc*32 + 4*f];
      es[4*f+0][k] = v.x; es[4*f+1][k] = v.y; es[4*f+2][k] = v.z; es[4*f+3][k] = v.w;
    }
    __syncthreads();
    #pragma unroll
    for (int d = 0; d < 32; ++d) {       // sequential d: deterministic sum order
      const float4 a4 = *(const float4*)&xs[d][ty*4];
      const float4 b0 = *(const float4*)&es[d][tx*4];
      const float4 b1 = *(const float4*)&es[d][64 + tx*4];
      const float a[4]  = {a4.x, a4.y, a4.z, a4.w};
      const float bb[8] = {b0.x, b0.y, b0.z, b0.w, b1.x, b1.y, b1.z, b1.w};
      #pragma unroll
      for (int i = 0; i < 4; ++i)
        #pragma unroll
        for (int j = 0; j < 8; ++j)
          acc[i][j] = fmaf(a[i], bb[j], acc[i][j]);
    }
  }

  const int kb0 = kb + tx*4, kb1 = kb + 64 + tx*4;
  const float4 h0 = *(const float4*)&halfe2[kb0];
  const float4 h1 = *(const float4*)&halfe2[kb1];
  const float hh[8] = {h0.x, h0.y, h0.z, h0.w, h1.x, h1.y, h1.z, h1.w};
  #pragma unroll
  for (int i = 0; i < 4; ++i) {
    float v = hh[0] - acc[i][0];
    int  vi = kb0;
    #pragma unroll
    for (int j = 1; j < 8; ++j) {
      const float w  = hh[j] - acc[i][j];
      const int   wk = (j < 4) ? (kb0 + j) : (kb1 + j - 4);
      if (w < v) { v = w; vi = wk; }     // ascending codes: strict < keeps first
    }
    #pragma unroll
    for (int off = 1; off < 16; off <<= 1) {
      const float ov = __shfl_xor(v, off, 64);
      const int   oi = __shfl_xor(vi, off, 64);
      if (ov < v || (ov == v && oi < vi)) { v = ov; vi = oi; }
    }
    if (tx == 0) {
      const unsigned long long key =
          ((unsigned long long)mono(v) << 32) | (unsigned)vi;
      atomicMin(&keys[s0 + ty*4 + i], key);
    }
  }
}

// ---- apply: decode refined keys back into IDX ------------------------------
__global__ void vq_apply(float* __restrict__ out) {
  const int slot = blockIdx.x * 256 + threadIdx.x;
  const int nf0 = *(const int*)&out[CNT_OFF];
  const int nf  = nf0 < CAPF ? nf0 : CAPF;
  if (slot >= nf) return;
  const int q = ((const int*)&out[LIST_OFF])[slot];
  const unsigned long long k = ((const unsigned long long*)&out[KEY_OFF])[slot];
  if (k != ~0ull) out[IDX_OFF + q] = (float)(unsigned)(k & 0xFFFFFFFFull);
}

// ---- gather quantize rows, float4 stores (overwrites all d_out scratch) ----
__global__ __launch_bounds__(256)
void vq_gather(const float* __restrict__ embed, float* __restrict__ out) {
  __shared__ int idx_s[128];
  const int t  = threadIdx.x;
  const int q0 = blockIdx.x * 128;
  const int b  = q0 >> 12, n0 = q0 & (NNN-1);
  if (t < 128) idx_s[t] = (int)out[IDX_OFF + q0 + t];
  __syncthreads();
  float* qb = out + (size_t)b * DDIM * NNN + n0;
  for (int j = 0; j < 64; ++j) {
    const int id = t + 256*j;
    const int d = id >> 5, n4 = (id & 31) * 4;
    float4 v;
    v.x = embed[(size_t)idx_s[n4+0]*DDIM + d];
    v.y = embed[(size_t)idx_s[n4+1]*DDIM + d];
    v.z = embed[(size_t)idx_s[n4+2]*DDIM + d];
    v.w = embed[(size_t)idx_s[n4+3]*DDIM + d];
    *(float4*)&qb[(size_t)d * NNN + n4] = v;
  }
}

extern "C" void kernel_launch(void* const* d_in, const int* in_sizes, int n_in,
                              void* d_out, int out_size, void* d_ws, size_t ws_size,
                              hipStream_t stream) {
  const float* x     = (const float*)d_in[0];   // [8, 512, 4096] fp32
  const float* embed = (const float*)d_in[1];   // [2048, 512] fp32
  float* out    = (float*)d_out;
  float* halfe2 = (float*)d_ws;                 // 8 KB scratch

  hipLaunchKernelGGL(conv_e,   dim3(KKK/4),   dim3(256), 0, stream, embed, halfe2, out);
  hipLaunchKernelGGL(conv_x,   dim3(4096),    dim3(256), 0, stream, x, out);
  hipLaunchKernelGGL(vq_main,  dim3((MMM/TMQ)*KSPLIT), dim3(256), 0, stream, halfe2, out);
  hipLaunchKernelGGL(vq_merge, dim3(MMM/256), dim3(256), 0, stream, out);
  hipLaunchKernelGGL(vq_prep,  dim3(256),     dim3(256), 0, stream, x, out);
  hipLaunchKernelGGL(vq_refine,dim3(16, CAPF/64), dim3(256), 0, stream, embed, halfe2, out);
  hipLaunchKernelGGL(vq_apply, dim3(CAPF/256),dim3(256), 0, stream, out);
  hipLaunchKernelGGL(vq_gather,dim3(MMM/128), dim3(256), 0, stream, embed, out);
}

// Round 3
// 320.040 us; speedup vs baseline: 1.1381x; 1.0237x over previous
//
#include <hip/hip_runtime.h>
#include <math.h>

#define DDIM 512
#define NNN  4096
#define KKK  2048
#define MMM  32768          // 8*4096 queries

#define TMQ  128            // queries per block (main)
#define TNC  256            // codes per k-tile (main)
#define BK   32             // d per staging round (main)
#define KSPLIT 2
#define KHALF (KKK/KSPLIT)  // 1024
#define NKT  (KHALF/TNC)    // 4
#define NDR  (DDIM/BK)      // 16
#define TOTR (NKT*NDR)      // 64 pipelined rounds per block
#define BUFS ((TMQ+TNC)*BK) // 12288 shorts = 24 KB per buffer
#define NBUF 3              // 2-round-deep prefetch (counted vmcnt)
#define TAU  0.25f          // flag margin for exact re-resolve
#define CAPF 4096           // flagged-query capacity

// d_out scratch layout (floats) inside the quantize region [0, 16777216),
// fully overwritten by the final gather:
#define XH_OFF   0                      // x^T bf16 [m][d]: 8388608 floats
#define EH_OFF   8388608                // embed bf16 [k][d]: 524288 floats
#define PART_OFF (EH_OFF + 524288)      // per (q,ks) triple: MMM*KSPLIT*4 floats
#define XF_OFF   (PART_OFF + MMM*KSPLIT*4)  // compact fp32 x [slot][d]: CAPF*512
#define KEY_OFF  (XF_OFF + 2097152)     // CAPF u64 keys (byte off %8 == 0)
#define LIST_OFF (KEY_OFF + 8192)       // flagged-query list (ints)
#define CNT_OFF  (LIST_OFF + CAPF)      // atomic counter (int)
#define IDX_OFF  ((size_t)MMM * DDIM)   // output 1: indices as float

typedef short short8v __attribute__((ext_vector_type(8)));
typedef float f32x4   __attribute__((ext_vector_type(4)));

__device__ inline unsigned short f2bf(float f) {          // fp32 -> bf16 RNE
  unsigned u = __float_as_uint(f);
  u = u + 0x7FFFu + ((u >> 16) & 1u);
  return (unsigned short)(u >> 16);
}

// async global->LDS, 16B per lane; LDS dest = uniform base + lane*16
__device__ inline void gl_lds16(const short* g, short* l) {
  __builtin_amdgcn_global_load_lds(
      (const __attribute__((address_space(1))) unsigned int*)g,
      (__attribute__((address_space(3))) unsigned int*)l, 16, 0, 0);
}

__device__ inline unsigned mono(float f) {   // monotone float -> uint
  unsigned u = __float_as_uint(f);
  return (u & 0x80000000u) ? ~u : (u | 0x80000000u);
}

// ---- fused: x transpose->bf16 plane  +  embed->bf16 plane / halfe2 / init --
// blocks [0,4096): conv_x work; blocks [4096,4608): conv_e work.
__global__ __launch_bounds__(256)
void conv_xe(const float* __restrict__ x, const float* __restrict__ embed,
             float* __restrict__ halfe2, float* __restrict__ out) {
  __shared__ float xt[64][65];          // +1 pad: conflict-free column reads
  const int t = threadIdx.x;

  if (blockIdx.x >= 4096) {             // ---- embed part (512 blocks) ----
    const int blk = blockIdx.x - 4096;
    const int gid = blk * 256 + t;
    if (gid == 0) *(int*)&out[CNT_OFF] = 0;
    if (gid < CAPF) ((unsigned long long*)&out[KEY_OFF])[gid] = ~0ull;
    const int row  = blk * 4 + (t >> 6);
    const int lane = t & 63;
    const float* e = embed + (size_t)row * DDIM;
    short* eh = (short*)&out[EH_OFF];
    const float4 v0 = *(const float4*)&e[lane*8];
    const float4 v1 = *(const float4*)&e[lane*8 + 4];
    const float vv[8] = {v0.x,v0.y,v0.z,v0.w,v1.x,v1.y,v1.z,v1.w};
    float s = 0.f;
    short8v p;
    #pragma unroll
    for (int i = 0; i < 8; ++i) { s = fmaf(vv[i], vv[i], s); p[i] = (short)f2bf(vv[i]); }
    *(short8v*)&eh[(size_t)row * DDIM + lane*8] = p;
    #pragma unroll
    for (int off = 32; off >= 1; off >>= 1) s += __shfl_xor(s, off, 64);
    if (lane == 0) halfe2[row] = 0.5f * s;
    return;
  }

  // ---- x part (4096 blocks): [b][d][n] -> xh[m][d], m = b*4096+n ----
  const int nt = blockIdx.x & 63, dt = (blockIdx.x >> 6) & 7, b = blockIdx.x >> 9;
  const int n0 = nt * 64, d0 = dt * 64;
  const float* xb = x + ((size_t)b * DDIM + d0) * NNN + n0;
  #pragma unroll
  for (int i = 0; i < 4; ++i) {
    const int fid = t + 256*i;
    const int dl = fid >> 4, n4 = (fid & 15) * 4;
    const float4 v = *(const float4*)&xb[(size_t)dl * NNN + n4];
    xt[dl][n4+0] = v.x; xt[dl][n4+1] = v.y; xt[dl][n4+2] = v.z; xt[dl][n4+3] = v.w;
  }
  __syncthreads();
  short* xh = (short*)&out[XH_OFF];
  const int m0 = b * NNN + n0;
  #pragma unroll
  for (int i = 0; i < 2; ++i) {
    const int id = t + 256*i;
    const int m = id >> 3, ch = (id & 7) * 8;
    short8v p;
    #pragma unroll
    for (int j = 0; j < 8; ++j) p[j] = (short)f2bf(xt[ch + j][m]);
    *(short8v*)&xh[(size_t)(m0 + m) * DDIM + d0 + ch] = p;
  }
}

// ---- main: triple-buffered counted-vmcnt bf16 MFMA GEMM + deferred argmin --
// score[q][k] = 0.5*||e_k||^2 - <x_q, e_k>
// T3+T4: STAGE(R+2) issued in round R; steady-state wait is vmcnt(6) (only the
// newest 6 loads may remain in flight), so each stage has ~2 full rounds of
// compute to cover HBM-miss latency; vmcnt(0) only in the last two rounds.
// Write-hazard safe: buf[(R+2)%3] was last READ in round R-1, whose end-of-round
// barrier precedes the STAGE issue; loads cannot land before issue.
__global__ __launch_bounds__(256, 2)
void vq_main(const float* __restrict__ halfe2, float* __restrict__ out) {
  __shared__ __align__(16) short lds[NBUF * BUFS];   // 72 KB (2 blocks/CU = 144 <= 160)
  const short* xh = (const short*)&out[XH_OFF];
  const short* eh = (const short*)&out[EH_OFF];

  const int t  = threadIdx.x;
  const int mb = blockIdx.x >> 1, ks = blockIdx.x & 1;
  const int q0 = mb * TMQ;
  const int kbase = ks * KHALF;
  const int w = t >> 6, lane = t & 63;
  const int mw = (w >> 1) * 64, nw = (w & 1) * 128;   // wave 64x128 sub-tile
  const int l15 = lane & 15, lg = lane >> 4;
  const int c0 = w * 6;                                // 6 1-KB chunks per wave
  const int lrow = lane >> 2;                          // row within 16-row chunk
  // physical slot (lane&3) holds logical quad (p - (row>>1)) & 3:
  const int scol = ((((lane & 3) - ((lane >> 3) & 3)) & 3) << 3);

  // deferred per-lane running (best, idx, 2nd-best) for 16 queries/lane
  float rv1[16], rv2[16]; int ri1[16];
  #pragma unroll
  for (int i = 0; i < 16; ++i) { rv1[i] = INFINITY; rv2[i] = INFINITY; ri1[i] = 0x7FFFFFFF; }

  // stage round R (24 KB: 128 q-rows + 256 e-rows x 32 d) into buffer tb
  auto STAGE = [&](int R, int tb) {
    const int kt_ = R >> 4, dr_ = R & 15;
    const int kb_ = kbase + kt_ * TNC;
    const int d0_ = dr_ * BK;
    short* buf = lds + tb * BUFS;
    #pragma unroll
    for (int j = 0; j < 6; ++j) {
      const int c = c0 + j;
      const short* src = (c < 8)
        ? xh + (size_t)(q0 + c*16 + lrow) * DDIM + d0_ + scol
        : eh + (size_t)(kb_ + (c-8)*16 + lrow) * DDIM + d0_ + scol;
      gl_lds16(src, buf + c * 512);
    }
  };

  // prologue: 2-deep fill; wait for buf0 (6 newest = STAGE(1) may stay in flight)
  STAGE(0, 0);
  STAGE(1, 1);
  asm volatile("s_waitcnt vmcnt(6)" ::: "memory");
  __builtin_amdgcn_s_barrier();

  int bi = 0;                                          // buffer holding round R
  for (int kt = 0; kt < NKT; ++kt) {
    const int kb = kbase + kt * TNC;
    f32x4 acc[4][8];
    #pragma unroll
    for (int mi = 0; mi < 4; ++mi)
      #pragma unroll
      for (int ni = 0; ni < 8; ++ni) acc[mi][ni] = (f32x4){0.f,0.f,0.f,0.f};

    for (int dr = 0; dr < NDR; ++dr) {
      const int R = kt * NDR + dr;
      const int nb = bi ? bi - 1 : 2;                  // (bi+2)%3
      if (R + 2 < TOTR) STAGE(R + 2, nb);              // 2-round-deep prefetch
      const short* xs = lds + bi * BUFS;
      const short* es = xs + TMQ * BK;
      short8v bfr[8];
      #pragma unroll
      for (int ni = 0; ni < 8; ++ni) {
        const int row = nw + ni*16 + l15;
        bfr[ni] = *(const short8v*)&es[row*32 + (((lg + (row >> 1)) & 3) << 3)];
      }
      #pragma unroll
      for (int mi = 0; mi < 4; ++mi) {
        const int row = mw + mi*16 + l15;
        const short8v a = *(const short8v*)&xs[row*32 + (((lg + (row >> 1)) & 3) << 3)];
        #pragma unroll
        for (int ni = 0; ni < 8; ++ni)
          acc[mi][ni] = __builtin_amdgcn_mfma_f32_16x16x32_bf16(a, bfr[ni], acc[mi][ni], 0,0,0);
      }
      // counted wait: all but the newest 6 loads (STAGE(R+2)) must have landed
      // -> STAGE(R+1) complete before any wave enters round R+1.
      if (R + 2 < TOTR) { asm volatile("s_waitcnt vmcnt(6)" ::: "memory"); }
      else              { asm volatile("s_waitcnt vmcnt(0)" ::: "memory"); }
      __builtin_amdgcn_s_barrier();
      bi = (bi == 2) ? 0 : bi + 1;
    }

    // per-k-tile: per-lane tournament only (no cross-lane traffic);
    // candidate indices strictly ascend -> strict < keeps first index
    float he[8];
    #pragma unroll
    for (int ni = 0; ni < 8; ++ni) he[ni] = halfe2[kb + nw + ni*16 + l15];
    #pragma unroll
    for (int mi = 0; mi < 4; ++mi) {
      #pragma unroll
      for (int r = 0; r < 4; ++r) {
        const int e_ = mi*4 + r;
        #pragma unroll
        for (int ni = 0; ni < 8; ++ni) {
          const float sc = he[ni] - acc[mi][ni][r];
          if (sc < rv1[e_]) { rv2[e_] = rv1[e_]; rv1[e_] = sc; ri1[e_] = kb + nw + ni*16 + l15; }
          else rv2[e_] = fminf(rv2[e_], sc);
        }
      }
    }
  }

  // once: cross-lane merge over the 16 code-columns (within each 16-lane group)
  #pragma unroll
  for (int e_ = 0; e_ < 16; ++e_) {
    float v1 = rv1[e_], v2 = rv2[e_]; int i1 = ri1[e_];
    #pragma unroll
    for (int off = 1; off < 16; off <<= 1) {
      const float ov1 = __shfl_xor(v1, off, 64);
      const int   oi1 = __shfl_xor(i1, off, 64);
      const float ov2 = __shfl_xor(v2, off, 64);
      if (ov1 < v1 || (ov1 == v1 && oi1 < i1)) { v2 = fminf(v1, ov2); v1 = ov1; i1 = oi1; }
      else v2 = fminf(v2, ov1);
    }
    rv1[e_] = v1; rv2[e_] = v2; ri1[e_] = i1;
  }

  // merge the two code-half waves (w&1) per query via LDS; store partial triple
  __syncthreads();
  float* mbuf = (float*)lds;   // [128 q][2 halves][3]
  if (l15 == 0) {
    #pragma unroll
    for (int mi = 0; mi < 4; ++mi)
      #pragma unroll
      for (int r = 0; r < 4; ++r) {
        const int ql = mw + mi*16 + lg*4 + r;
        const int slot = (ql*2 + (w & 1))*3;
        const int e_ = mi*4 + r;
        mbuf[slot+0] = rv1[e_];
        mbuf[slot+1] = __int_as_float(ri1[e_]);
        mbuf[slot+2] = rv2[e_];
      }
  }
  __syncthreads();
  if (t < TMQ) {
    const float a1 = mbuf[t*6+0]; const int ai = __float_as_int(mbuf[t*6+1]); const float a2 = mbuf[t*6+2];
    const float b1 = mbuf[t*6+3]; const int bi2 = __float_as_int(mbuf[t*6+4]); const float b2 = mbuf[t*6+5];
    float v1, v2; int i1;
    if (b1 < a1 || (b1 == a1 && bi2 < ai)) { v1 = b1; i1 = bi2; v2 = fminf(a1, b2); }
    else                                   { v1 = a1; i1 = ai;  v2 = fminf(a2, b1); }
    f32x4 st = {v1, (float)i1, v2, 0.f};
    *(f32x4*)&out[PART_OFF + ((size_t)(q0 + t)*KSPLIT + ks)*4] = st;
  }
}

// ---- merge K-split partials; write index; flag ambiguous queries -----------
__global__ void vq_merge(float* __restrict__ out) {
  const int q = blockIdx.x * 256 + threadIdx.x;
  float v1, v2; int i1;
  {
    const f32x4 p = *(const f32x4*)&out[PART_OFF + (size_t)q*(KSPLIT*4)];
    v1 = p[0]; i1 = (int)p[1]; v2 = p[2];
  }
  #pragma unroll
  for (int s = 1; s < KSPLIT; ++s) {
    const f32x4 p = *(const f32x4*)&out[PART_OFF + (size_t)q*(KSPLIT*4) + s*4];
    const float b1 = p[0]; const int bi = (int)p[1]; const float b2 = p[2];
    // splits cover disjoint ascending code ranges; sequential merge keeps
    // the exact global (best, idx, 2nd-best).
    if (b1 < v1 || (b1 == v1 && bi < i1)) { v2 = fminf(v1, b2); v1 = b1; i1 = bi; }
    else v2 = fminf(v2, b1);
  }
  out[IDX_OFF + q] = (float)i1;
  if (v2 - v1 < TAU) {
    const int pos = atomicAdd((int*)&out[CNT_OFF], 1);
    if (pos < CAPF) ((int*)&out[LIST_OFF])[pos] = q;
  }
}

// ---- prep: compact flagged x rows into fp32 plane XF[slot][d] --------------
// reads scattered (inherent to x layout, L3-resident); writes coalesced 256B/wave
__global__ __launch_bounds__(256)
void vq_prep(const float* __restrict__ x, float* __restrict__ out) {
  const int nf0 = *(const int*)&out[CNT_OFF];
  const int nf  = nf0 < CAPF ? nf0 : CAPF;
  const int* list = (const int*)&out[LIST_OFF];
  float* XF = &out[XF_OFF];
  const int wid  = (blockIdx.x * 256 + threadIdx.x) >> 6;   // 1024 waves
  const int lane = threadIdx.x & 63;
  for (int s = wid; s < nf; s += 1024) {
    const int q = list[s];
    const int b = q >> 12, n = q & (NNN - 1);
    const float* xb = x + (size_t)b * DDIM * NNN + n;
    #pragma unroll
    for (int j = 0; j < 8; ++j) {
      const int d = lane + 64*j;
      XF[(size_t)s * DDIM + d] = xb[(size_t)d * NNN];
    }
  }
}

// ---- refine: exact fp32 microtile GEMM over flagged slots ------------------
// block = 64 slots x 128 codes; 4x8 register microtile;
// deterministic cross-block merge via monotone-key atomicMin.
__global__ __launch_bounds__(256, 2)
void vq_refine(const float* __restrict__ embed, const float* __restrict__ halfe2,
               float* __restrict__ out) {
  const int nf0 = *(const int*)&out[CNT_OFF];
  const int nf  = nf0 < CAPF ? nf0 : CAPF;
  const int s0  = blockIdx.y * 64;
  if (s0 >= nf) return;
  __shared__ float xs[32][68];   // stride 68: float4-aligned, <=4-way stage writes
  __shared__ float es[32][132];
  const int t = threadIdx.x, tx = t & 15, ty = t >> 4;
  const int kb = blockIdx.x * 128;
  const float* XF = &out[XF_OFF];
  unsigned long long* keys = (unsigned long long*)&out[KEY_OFF];

  float acc[4][8];
  #pragma unroll
  for (int i = 0; i < 4; ++i)
    #pragma unroll
    for (int j = 0; j < 8; ++j) acc[i][j] = 0.f;

  for (int dc = 0; dc < 16; ++dc) {
    __syncthreads();
    #pragma unroll
    for (int i = 0; i < 2; ++i) {        // xs[d][m] <- XF[s0+m][.] row float4 reads
      const int l = t + 256*i;           // 512 float4
      const int m = l >> 3, f = l & 7;
      const float4 v = *(const float4*)&XF[(size_t)(s0 + m) * DDIM + dc*32 + 4*f];
      xs[4*f+0][m] = v.x; xs[4*f+1][m] = v.y; xs[4*f+2][m] = v.z; xs[4*f+3][m] = v.w;
    }
    #pragma unroll
    for (int i = 0; i < 4; ++i) {        // es[d][k] <- embed rows (float4)
      const int l = t + 256*i;
      const int k = l >> 3, f = l & 7;
      const float4 v = *(const float4*)&embed[(size_t)(kb + k)*DDIM + dc*32 + 4*f];
      es[4*f+0][k] = v.x; es[4*f+1][k] = v.y; es[4*f+2][k] = v.z; es[4*f+3][k] = v.w;
    }
    __syncthreads();
    #pragma unroll
    for (int d = 0; d < 32; ++d) {       // sequential d: deterministic sum order
      const float4 a4 = *(const float4*)&xs[d][ty*4];
      const float4 b0 = *(const float4*)&es[d][tx*4];
      const float4 b1 = *(const float4*)&es[d][64 + tx*4];
      const float a[4]  = {a4.x, a4.y, a4.z, a4.w};
      const float bb[8] = {b0.x, b0.y, b0.z, b0.w, b1.x, b1.y, b1.z, b1.w};
      #pragma unroll
      for (int i = 0; i < 4; ++i)
        #pragma unroll
        for (int j = 0; j < 8; ++j)
          acc[i][j] = fmaf(a[i], bb[j], acc[i][j]);
    }
  }

  const int kb0 = kb + tx*4, kb1 = kb + 64 + tx*4;
  const float4 h0 = *(const float4*)&halfe2[kb0];
  const float4 h1 = *(const float4*)&halfe2[kb1];
  const float hh[8] = {h0.x, h0.y, h0.z, h0.w, h1.x, h1.y, h1.z, h1.w};
  #pragma unroll
  for (int i = 0; i < 4; ++i) {
    float v = hh[0] - acc[i][0];
    int  vi = kb0;
    #pragma unroll
    for (int j = 1; j < 8; ++j) {
      const float w  = hh[j] - acc[i][j];
      const int   wk = (j < 4) ? (kb0 + j) : (kb1 + j - 4);
      if (w < v) { v = w; vi = wk; }     // ascending codes: strict < keeps first
    }
    #pragma unroll
    for (int off = 1; off < 16; off <<= 1) {
      const float ov = __shfl_xor(v, off, 64);
      const int   oi = __shfl_xor(vi, off, 64);
      if (ov < v || (ov == v && oi < vi)) { v = ov; vi = oi; }
    }
    if (tx == 0) {
      const unsigned long long key =
          ((unsigned long long)mono(v) << 32) | (unsigned)vi;
      atomicMin(&keys[s0 + ty*4 + i], key);
    }
  }
}

// ---- apply: decode refined keys back into IDX ------------------------------
__global__ void vq_apply(float* __restrict__ out) {
  const int slot = blockIdx.x * 256 + threadIdx.x;
  const int nf0 = *(const int*)&out[CNT_OFF];
  const int nf  = nf0 < CAPF ? nf0 : CAPF;
  if (slot >= nf) return;
  const int q = ((const int*)&out[LIST_OFF])[slot];
  const unsigned long long k = ((const unsigned long long*)&out[KEY_OFF])[slot];
  if (k != ~0ull) out[IDX_OFF + q] = (float)(unsigned)(k & 0xFFFFFFFFull);
}

// ---- gather quantize rows, float4 stores (overwrites all d_out scratch) ----
__global__ __launch_bounds__(256)
void vq_gather(const float* __restrict__ embed, float* __restrict__ out) {
  __shared__ int idx_s[128];
  const int t  = threadIdx.x;
  const int q0 = blockIdx.x * 128;
  const int b  = q0 >> 12, n0 = q0 & (NNN-1);
  if (t < 128) idx_s[t] = (int)out[IDX_OFF + q0 + t];
  __syncthreads();
  float* qb = out + (size_t)b * DDIM * NNN + n0;
  for (int j = 0; j < 64; ++j) {
    const int id = t + 256*j;
    const int d = id >> 5, n4 = (id & 31) * 4;
    float4 v;
    v.x = embed[(size_t)idx_s[n4+0]*DDIM + d];
    v.y = embed[(size_t)idx_s[n4+1]*DDIM + d];
    v.z = embed[(size_t)idx_s[n4+2]*DDIM + d];
    v.w = embed[(size_t)idx_s[n4+3]*DDIM + d];
    *(float4*)&qb[(size_t)d * NNN + n4] = v;
  }
}

extern "C" void kernel_launch(void* const* d_in, const int* in_sizes, int n_in,
                              void* d_out, int out_size, void* d_ws, size_t ws_size,
                              hipStream_t stream) {
  const float* x     = (const float*)d_in[0];   // [8, 512, 4096] fp32
  const float* embed = (const float*)d_in[1];   // [2048, 512] fp32
  float* out    = (float*)d_out;
  float* halfe2 = (float*)d_ws;                 // 8 KB scratch

  hipLaunchKernelGGL(conv_xe, dim3(4096 + KKK/4), dim3(256), 0, stream, x, embed, halfe2, out);
  hipLaunchKernelGGL(vq_main,  dim3((MMM/TMQ)*KSPLIT), dim3(256), 0, stream, halfe2, out);
  hipLaunchKernelGGL(vq_merge, dim3(MMM/256), dim3(256), 0, stream, out);
  hipLaunchKernelGGL(vq_prep,  dim3(256),     dim3(256), 0, stream, x, out);
  hipLaunchKernelGGL(vq_refine,dim3(16, CAPF/64), dim3(256), 0, stream, embed, halfe2, out);
  hipLaunchKernelGGL(vq_apply, dim3(CAPF/256),dim3(256), 0, stream, out);
  hipLaunchKernelGGL(vq_gather,dim3(MMM/128), dim3(256), 0, stream, embed, out);
}

// Round 4
// 302.075 us; speedup vs baseline: 1.2058x; 1.0595x over previous
//
#include <hip/hip_runtime.h>
#include <math.h>

#define DDIM 512
#define NNN  4096
#define KKK  2048
#define MMM  32768          // 8*4096 queries

#define TMQ  128            // queries per block (main)
#define TNC  256            // codes per k-tile (main)
#define BK   32             // d per staging round (main)
#define KSPLIT 2
#define KHALF (KKK/KSPLIT)  // 1024
#define NKT  (KHALF/TNC)    // 4
#define NDR  (DDIM/BK)      // 16
#define TOTR (NKT*NDR)      // 64 pipelined rounds per block
#define BUFS ((TMQ+TNC)*BK) // 12288 shorts = 24 KB per buffer
#define NBUF 3              // 2-round-deep prefetch (counted vmcnt)
#define TAU  0.05f          // fp16 scores: sigma_diff ~0.013 -> 3.9 sigma margin
                            // (proven-safe bf16 config was 2.4 sigma at TAU=0.25)
#define CAPF 4096           // flagged-query capacity

// d_out scratch layout (floats) inside the quantize region [0, 16777216),
// fully overwritten by the final gather:
#define XH_OFF   0                      // x^T fp16 [m][d]: 8388608 floats
#define EH_OFF   8388608                // embed fp16 [k][d]: 524288 floats
#define PART_OFF (EH_OFF + 524288)      // per (q,ks) triple: MMM*KSPLIT*4 floats
#define XF_OFF   (PART_OFF + MMM*KSPLIT*4)  // compact fp32 x [slot][d]: CAPF*512
#define KEY_OFF  (XF_OFF + 2097152)     // CAPF u64 keys (byte off %8 == 0)
#define LIST_OFF (KEY_OFF + 8192)       // flagged-query list (ints)
#define CNT_OFF  (LIST_OFF + CAPF)      // atomic counter (int)
#define IDX_OFF  ((size_t)MMM * DDIM)   // output 1: indices as float

typedef short short8v __attribute__((ext_vector_type(8)));
typedef _Float16 half8v __attribute__((ext_vector_type(8)));
typedef float f32x4   __attribute__((ext_vector_type(4)));

__device__ inline unsigned short f2h(float f) {           // fp32 -> fp16 RNE
  _Float16 h = (_Float16)f;                                // v_cvt_f16_f32
  return *(unsigned short*)&h;
}

// async global->LDS, 16B per lane; LDS dest = uniform base + lane*16
__device__ inline void gl_lds16(const short* g, short* l) {
  __builtin_amdgcn_global_load_lds(
      (const __attribute__((address_space(1))) unsigned int*)g,
      (__attribute__((address_space(3))) unsigned int*)l, 16, 0, 0);
}

__device__ inline unsigned mono(float f) {   // monotone float -> uint
  unsigned u = __float_as_uint(f);
  return (u & 0x80000000u) ? ~u : (u | 0x80000000u);
}

// ---- fused: x transpose->fp16 plane  +  embed->fp16 plane / halfe2 / init --
// blocks [0,4096): conv_x work; blocks [4096,4608): conv_e work.
__global__ __launch_bounds__(256)
void conv_xe(const float* __restrict__ x, const float* __restrict__ embed,
             float* __restrict__ halfe2, float* __restrict__ out) {
  __shared__ float xt[64][65];          // +1 pad: conflict-free column reads
  const int t = threadIdx.x;

  if (blockIdx.x >= 4096) {             // ---- embed part (512 blocks) ----
    const int blk = blockIdx.x - 4096;
    const int gid = blk * 256 + t;
    if (gid == 0) *(int*)&out[CNT_OFF] = 0;
    if (gid < CAPF) ((unsigned long long*)&out[KEY_OFF])[gid] = ~0ull;
    const int row  = blk * 4 + (t >> 6);
    const int lane = t & 63;
    const float* e = embed + (size_t)row * DDIM;
    short* eh = (short*)&out[EH_OFF];
    const float4 v0 = *(const float4*)&e[lane*8];
    const float4 v1 = *(const float4*)&e[lane*8 + 4];
    const float vv[8] = {v0.x,v0.y,v0.z,v0.w,v1.x,v1.y,v1.z,v1.w};
    float s = 0.f;
    short8v p;
    #pragma unroll
    for (int i = 0; i < 8; ++i) { s = fmaf(vv[i], vv[i], s); p[i] = (short)f2h(vv[i]); }
    *(short8v*)&eh[(size_t)row * DDIM + lane*8] = p;
    #pragma unroll
    for (int off = 32; off >= 1; off >>= 1) s += __shfl_xor(s, off, 64);
    if (lane == 0) halfe2[row] = 0.5f * s;
    return;
  }

  // ---- x part (4096 blocks): [b][d][n] -> xh[m][d], m = b*4096+n ----
  const int nt = blockIdx.x & 63, dt = (blockIdx.x >> 6) & 7, b = blockIdx.x >> 9;
  const int n0 = nt * 64, d0 = dt * 64;
  const float* xb = x + ((size_t)b * DDIM + d0) * NNN + n0;
  #pragma unroll
  for (int i = 0; i < 4; ++i) {
    const int fid = t + 256*i;
    const int dl = fid >> 4, n4 = (fid & 15) * 4;
    const float4 v = *(const float4*)&xb[(size_t)dl * NNN + n4];
    xt[dl][n4+0] = v.x; xt[dl][n4+1] = v.y; xt[dl][n4+2] = v.z; xt[dl][n4+3] = v.w;
  }
  __syncthreads();
  short* xh = (short*)&out[XH_OFF];
  const int m0 = b * NNN + n0;
  #pragma unroll
  for (int i = 0; i < 2; ++i) {
    const int id = t + 256*i;
    const int m = id >> 3, ch = (id & 7) * 8;
    short8v p;
    #pragma unroll
    for (int j = 0; j < 8; ++j) p[j] = (short)f2h(xt[ch + j][m]);
    *(short8v*)&xh[(size_t)(m0 + m) * DDIM + d0 + ch] = p;
  }
}

// ---- main: triple-buffered counted-vmcnt fp16 MFMA GEMM + deferred argmin --
// score[q][k] = 0.5*||e_k||^2 - <x_q, e_k>   (cross term in fp16, f32 accum)
__global__ __launch_bounds__(256, 2)
void vq_main(const float* __restrict__ halfe2, float* __restrict__ out) {
  __shared__ __align__(16) short lds[NBUF * BUFS];   // 72 KB
  const short* xh = (const short*)&out[XH_OFF];
  const short* eh = (const short*)&out[EH_OFF];

  const int t  = threadIdx.x;
  const int mb = blockIdx.x >> 1, ks = blockIdx.x & 1;
  const int q0 = mb * TMQ;
  const int kbase = ks * KHALF;
  const int w = t >> 6, lane = t & 63;
  const int mw = (w >> 1) * 64, nw = (w & 1) * 128;   // wave 64x128 sub-tile
  const int l15 = lane & 15, lg = lane >> 4;
  const int c0 = w * 6;                                // 6 1-KB chunks per wave
  const int lrow = lane >> 2;                          // row within 16-row chunk
  // physical slot (lane&3) holds logical quad (p - (row>>1)) & 3:
  const int scol = ((((lane & 3) - ((lane >> 3) & 3)) & 3) << 3);

  // deferred per-lane running (best, idx, 2nd-best) for 16 queries/lane
  float rv1[16], rv2[16]; int ri1[16];
  #pragma unroll
  for (int i = 0; i < 16; ++i) { rv1[i] = INFINITY; rv2[i] = INFINITY; ri1[i] = 0x7FFFFFFF; }

  // stage round R (24 KB: 128 q-rows + 256 e-rows x 32 d) into buffer tb
  auto STAGE = [&](int R, int tb) {
    const int kt_ = R >> 4, dr_ = R & 15;
    const int kb_ = kbase + kt_ * TNC;
    const int d0_ = dr_ * BK;
    short* buf = lds + tb * BUFS;
    #pragma unroll
    for (int j = 0; j < 6; ++j) {
      const int c = c0 + j;
      const short* src = (c < 8)
        ? xh + (size_t)(q0 + c*16 + lrow) * DDIM + d0_ + scol
        : eh + (size_t)(kb_ + (c-8)*16 + lrow) * DDIM + d0_ + scol;
      gl_lds16(src, buf + c * 512);
    }
  };

  // prologue: 2-deep fill; wait for buf0 (6 newest = STAGE(1) may stay in flight)
  STAGE(0, 0);
  STAGE(1, 1);
  asm volatile("s_waitcnt vmcnt(6)" ::: "memory");
  __builtin_amdgcn_s_barrier();

  int bi = 0;                                          // buffer holding round R
  for (int kt = 0; kt < NKT; ++kt) {
    const int kb = kbase + kt * TNC;
    f32x4 acc[4][8];
    #pragma unroll
    for (int mi = 0; mi < 4; ++mi)
      #pragma unroll
      for (int ni = 0; ni < 8; ++ni) acc[mi][ni] = (f32x4){0.f,0.f,0.f,0.f};

    for (int dr = 0; dr < NDR; ++dr) {
      const int R = kt * NDR + dr;
      const int nb = bi ? bi - 1 : 2;                  // (bi+2)%3
      if (R + 2 < TOTR) STAGE(R + 2, nb);              // 2-round-deep prefetch
      const short* xs = lds + bi * BUFS;
      const short* es = xs + TMQ * BK;
      half8v bfr[8];
      #pragma unroll
      for (int ni = 0; ni < 8; ++ni) {
        const int row = nw + ni*16 + l15;
        bfr[ni] = *(const half8v*)&es[row*32 + (((lg + (row >> 1)) & 3) << 3)];
      }
      #pragma unroll
      for (int mi = 0; mi < 4; ++mi) {
        const int row = mw + mi*16 + l15;
        const half8v a = *(const half8v*)&xs[row*32 + (((lg + (row >> 1)) & 3) << 3)];
        #pragma unroll
        for (int ni = 0; ni < 8; ++ni)
          acc[mi][ni] = __builtin_amdgcn_mfma_f32_16x16x32_f16(a, bfr[ni], acc[mi][ni], 0,0,0);
      }
      // counted wait: all but the newest 6 loads (STAGE(R+2)) must have landed
      if (R + 2 < TOTR) { asm volatile("s_waitcnt vmcnt(6)" ::: "memory"); }
      else              { asm volatile("s_waitcnt vmcnt(0)" ::: "memory"); }
      __builtin_amdgcn_s_barrier();
      bi = (bi == 2) ? 0 : bi + 1;
    }

    // per-k-tile: per-lane tournament only (no cross-lane traffic);
    // candidate indices strictly ascend -> strict < keeps first index
    float he[8];
    #pragma unroll
    for (int ni = 0; ni < 8; ++ni) he[ni] = halfe2[kb + nw + ni*16 + l15];
    #pragma unroll
    for (int mi = 0; mi < 4; ++mi) {
      #pragma unroll
      for (int r = 0; r < 4; ++r) {
        const int e_ = mi*4 + r;
        #pragma unroll
        for (int ni = 0; ni < 8; ++ni) {
          const float sc = he[ni] - acc[mi][ni][r];
          if (sc < rv1[e_]) { rv2[e_] = rv1[e_]; rv1[e_] = sc; ri1[e_] = kb + nw + ni*16 + l15; }
          else rv2[e_] = fminf(rv2[e_], sc);
        }
      }
    }
  }

  // once: cross-lane merge over the 16 code-columns (within each 16-lane group)
  #pragma unroll
  for (int e_ = 0; e_ < 16; ++e_) {
    float v1 = rv1[e_], v2 = rv2[e_]; int i1 = ri1[e_];
    #pragma unroll
    for (int off = 1; off < 16; off <<= 1) {
      const float ov1 = __shfl_xor(v1, off, 64);
      const int   oi1 = __shfl_xor(i1, off, 64);
      const float ov2 = __shfl_xor(v2, off, 64);
      if (ov1 < v1 || (ov1 == v1 && oi1 < i1)) { v2 = fminf(v1, ov2); v1 = ov1; i1 = oi1; }
      else v2 = fminf(v2, ov1);
    }
    rv1[e_] = v1; rv2[e_] = v2; ri1[e_] = i1;
  }

  // merge the two code-half waves (w&1) per query via LDS; store partial triple
  __syncthreads();
  float* mbuf = (float*)lds;   // [128 q][2 halves][3]
  if (l15 == 0) {
    #pragma unroll
    for (int mi = 0; mi < 4; ++mi)
      #pragma unroll
      for (int r = 0; r < 4; ++r) {
        const int ql = mw + mi*16 + lg*4 + r;
        const int slot = (ql*2 + (w & 1))*3;
        const int e_ = mi*4 + r;
        mbuf[slot+0] = rv1[e_];
        mbuf[slot+1] = __int_as_float(ri1[e_]);
        mbuf[slot+2] = rv2[e_];
      }
  }
  __syncthreads();
  if (t < TMQ) {
    const float a1 = mbuf[t*6+0]; const int ai = __float_as_int(mbuf[t*6+1]); const float a2 = mbuf[t*6+2];
    const float b1 = mbuf[t*6+3]; const int bi2 = __float_as_int(mbuf[t*6+4]); const float b2 = mbuf[t*6+5];
    float v1, v2; int i1;
    if (b1 < a1 || (b1 == a1 && bi2 < ai)) { v1 = b1; i1 = bi2; v2 = fminf(a1, b2); }
    else                                   { v1 = a1; i1 = ai;  v2 = fminf(a2, b1); }
    f32x4 st = {v1, (float)i1, v2, 0.f};
    *(f32x4*)&out[PART_OFF + ((size_t)(q0 + t)*KSPLIT + ks)*4] = st;
  }
}

// ---- merge K-split partials; write index; flag ambiguous queries -----------
__global__ void vq_merge(float* __restrict__ out) {
  const int q = blockIdx.x * 256 + threadIdx.x;
  float v1, v2; int i1;
  {
    const f32x4 p = *(const f32x4*)&out[PART_OFF + (size_t)q*(KSPLIT*4)];
    v1 = p[0]; i1 = (int)p[1]; v2 = p[2];
  }
  #pragma unroll
  for (int s = 1; s < KSPLIT; ++s) {
    const f32x4 p = *(const f32x4*)&out[PART_OFF + (size_t)q*(KSPLIT*4) + s*4];
    const float b1 = p[0]; const int bi = (int)p[1]; const float b2 = p[2];
    if (b1 < v1 || (b1 == v1 && bi < i1)) { v2 = fminf(v1, b2); v1 = b1; i1 = bi; }
    else v2 = fminf(v2, b1);
  }
  out[IDX_OFF + q] = (float)i1;
  if (v2 - v1 < TAU) {
    const int pos = atomicAdd((int*)&out[CNT_OFF], 1);
    if (pos < CAPF) ((int*)&out[LIST_OFF])[pos] = q;
  }
}

// ---- prep: compact flagged x rows into fp32 plane XF[slot][d] --------------
__global__ __launch_bounds__(256)
void vq_prep(const float* __restrict__ x, float* __restrict__ out) {
  const int nf0 = *(const int*)&out[CNT_OFF];
  const int nf  = nf0 < CAPF ? nf0 : CAPF;
  const int* list = (const int*)&out[LIST_OFF];
  float* XF = &out[XF_OFF];
  const int wid  = (blockIdx.x * 256 + threadIdx.x) >> 6;   // 1024 waves
  const int lane = threadIdx.x & 63;
  for (int s = wid; s < nf; s += 1024) {
    const int q = list[s];
    const int b = q >> 12, n = q & (NNN - 1);
    const float* xb = x + (size_t)b * DDIM * NNN + n;
    #pragma unroll
    for (int j = 0; j < 8; ++j) {
      const int d = lane + 64*j;
      XF[(size_t)s * DDIM + d] = xb[(size_t)d * NNN];
    }
  }
}

// ---- refine: exact fp32 microtile GEMM over flagged slots ------------------
__global__ __launch_bounds__(256, 2)
void vq_refine(const float* __restrict__ embed, const float* __restrict__ halfe2,
               float* __restrict__ out) {
  const int nf0 = *(const int*)&out[CNT_OFF];
  const int nf  = nf0 < CAPF ? nf0 : CAPF;
  const int s0  = blockIdx.y * 64;
  if (s0 >= nf) return;
  __shared__ float xs[32][68];   // stride 68: float4-aligned, <=4-way stage writes
  __shared__ float es[32][132];
  const int t = threadIdx.x, tx = t & 15, ty = t >> 4;
  const int kb = blockIdx.x * 128;
  const float* XF = &out[XF_OFF];
  unsigned long long* keys = (unsigned long long*)&out[KEY_OFF];

  float acc[4][8];
  #pragma unroll
  for (int i = 0; i < 4; ++i)
    #pragma unroll
    for (int j = 0; j < 8; ++j) acc[i][j] = 0.f;

  for (int dc = 0; dc < 16; ++dc) {
    __syncthreads();
    #pragma unroll
    for (int i = 0; i < 2; ++i) {        // xs[d][m] <- XF[s0+m][.] row float4 reads
      const int l = t + 256*i;           // 512 float4
      const int m = l >> 3, f = l & 7;
      const float4 v = *(const float4*)&XF[(size_t)(s0 + m) * DDIM + dc*32 + 4*f];
      xs[4*f+0][m] = v.x; xs[4*f+1][m] = v.y; xs[4*f+2][m] = v.z; xs[4*f+3][m] = v.w;
    }
    #pragma unroll
    for (int i = 0; i < 4; ++i) {        // es[d][k] <- embed rows (float4)
      const int l = t + 256*i;
      const int k = l >> 3, f = l & 7;
      const float4 v = *(const float4*)&embed[(size_t)(kb + k)*DDIM + dc*32 + 4*f];
      es[4*f+0][k] = v.x; es[4*f+1][k] = v.y; es[4*f+2][k] = v.z; es[4*f+3][k] = v.w;
    }
    __syncthreads();
    #pragma unroll
    for (int d = 0; d < 32; ++d) {       // sequential d: deterministic sum order
      const float4 a4 = *(const float4*)&xs[d][ty*4];
      const float4 b0 = *(const float4*)&es[d][tx*4];
      const float4 b1 = *(const float4*)&es[d][64 + tx*4];
      const float a[4]  = {a4.x, a4.y, a4.z, a4.w};
      const float bb[8] = {b0.x, b0.y, b0.z, b0.w, b1.x, b1.y, b1.z, b1.w};
      #pragma unroll
      for (int i = 0; i < 4; ++i)
        #pragma unroll
        for (int j = 0; j < 8; ++j)
          acc[i][j] = fmaf(a[i], bb[j], acc[i][j]);
    }
  }

  const int kb0 = kb + tx*4, kb1 = kb + 64 + tx*4;
  const float4 h0 = *(const float4*)&halfe2[kb0];
  const float4 h1 = *(const float4*)&halfe2[kb1];
  const float hh[8] = {h0.x, h0.y, h0.z, h0.w, h1.x, h1.y, h1.z, h1.w};
  #pragma unroll
  for (int i = 0; i < 4; ++i) {
    float v = hh[0] - acc[i][0];
    int  vi = kb0;
    #pragma unroll
    for (int j = 1; j < 8; ++j) {
      const float w  = hh[j] - acc[i][j];
      const int   wk = (j < 4) ? (kb0 + j) : (kb1 + j - 4);
      if (w < v) { v = w; vi = wk; }     // ascending codes: strict < keeps first
    }
    #pragma unroll
    for (int off = 1; off < 16; off <<= 1) {
      const float ov = __shfl_xor(v, off, 64);
      const int   oi = __shfl_xor(vi, off, 64);
      if (ov < v || (ov == v && oi < vi)) { v = ov; vi = oi; }
    }
    if (tx == 0) {
      const unsigned long long key =
          ((unsigned long long)mono(v) << 32) | (unsigned)vi;
      atomicMin(&keys[s0 + ty*4 + i], key);
    }
  }
}

// ---- apply: decode refined keys back into IDX ------------------------------
__global__ void vq_apply(float* __restrict__ out) {
  const int slot = blockIdx.x * 256 + threadIdx.x;
  const int nf0 = *(const int*)&out[CNT_OFF];
  const int nf  = nf0 < CAPF ? nf0 : CAPF;
  if (slot >= nf) return;
  const int q = ((const int*)&out[LIST_OFF])[slot];
  const unsigned long long k = ((const unsigned long long*)&out[KEY_OFF])[slot];
  if (k != ~0ull) out[IDX_OFF + q] = (float)(unsigned)(k & 0xFFFFFFFFull);
}

// ---- gather quantize rows, float4 stores (overwrites all d_out scratch) ----
__global__ __launch_bounds__(256)
void vq_gather(const float* __restrict__ embed, float* __restrict__ out) {
  __shared__ int idx_s[128];
  const int t  = threadIdx.x;
  const int q0 = blockIdx.x * 128;
  const int b  = q0 >> 12, n0 = q0 & (NNN-1);
  if (t < 128) idx_s[t] = (int)out[IDX_OFF + q0 + t];
  __syncthreads();
  float* qb = out + (size_t)b * DDIM * NNN + n0;
  for (int j = 0; j < 64; ++j) {
    const int id = t + 256*j;
    const int d = id >> 5, n4 = (id & 31) * 4;
    float4 v;
    v.x = embed[(size_t)idx_s[n4+0]*DDIM + d];
    v.y = embed[(size_t)idx_s[n4+1]*DDIM + d];
    v.z = embed[(size_t)idx_s[n4+2]*DDIM + d];
    v.w = embed[(size_t)idx_s[n4+3]*DDIM + d];
    *(float4*)&qb[(size_t)d * NNN + n4] = v;
  }
}

extern "C" void kernel_launch(void* const* d_in, const int* in_sizes, int n_in,
                              void* d_out, int out_size, void* d_ws, size_t ws_size,
                              hipStream_t stream) {
  const float* x     = (const float*)d_in[0];   // [8, 512, 4096] fp32
  const float* embed = (const float*)d_in[1];   // [2048, 512] fp32
  float* out    = (float*)d_out;
  float* halfe2 = (float*)d_ws;                 // 8 KB scratch

  hipLaunchKernelGGL(conv_xe, dim3(4096 + KKK/4), dim3(256), 0, stream, x, embed, halfe2, out);
  hipLaunchKernelGGL(vq_main,  dim3((MMM/TMQ)*KSPLIT), dim3(256), 0, stream, halfe2, out);
  hipLaunchKernelGGL(vq_merge, dim3(MMM/256), dim3(256), 0, stream, out);
  hipLaunchKernelGGL(vq_prep,  dim3(256),     dim3(256), 0, stream, x, out);
  hipLaunchKernelGGL(vq_refine,dim3(16, CAPF/64), dim3(256), 0, stream, embed, halfe2, out);
  hipLaunchKernelGGL(vq_apply, dim3(CAPF/256),dim3(256), 0, stream, out);
  hipLaunchKernelGGL(vq_gather,dim3(MMM/128), dim3(256), 0, stream, embed, out);
}

// Round 5
// 267.074 us; speedup vs baseline: 1.3638x; 1.1311x over previous
//
#include <hip/hip_runtime.h>
#include <math.h>

#define DDIM 512
#define NNN  4096
#define KKK  2048
#define MMM  32768          // 8*4096 queries

#define TMQ  128            // queries per block (main)
#define TNC  256            // codes per k-tile (main)
#define BK   32             // d per staging round (main)
#define KSPLIT 2
#define KHALF (KKK/KSPLIT)  // 1024
#define NKT  (KHALF/TNC)    // 4
#define NDR  (DDIM/BK)      // 16
#define TOTR (NKT*NDR)      // 64 pipelined rounds per block
#define BUFS ((TMQ+TNC)*BK) // 12288 shorts = 24 KB per buffer
#define NBUF 3              // 2-round-deep prefetch (counted vmcnt)
#define TAU  0.05f          // fp16 scores: sigma_diff ~0.013 -> 3.9 sigma margin
#define CAPF 4096           // flagged-query capacity

// d_out scratch layout (floats) inside the quantize region [0, 16777216),
// fully overwritten by the final gather:
#define XH_OFF   0                      // x^T fp16 [m][d]: 8388608 floats
#define EH_OFF   8388608                // embed fp16 [k][d]: 524288 floats
#define PART_OFF (EH_OFF + 524288)      // per (q,ks) triple: MMM*KSPLIT*4 floats
#define XF_OFF   (PART_OFF + MMM*KSPLIT*4)  // compact fp32 x [slot][d]: CAPF*512
#define KEY_OFF  (XF_OFF + 2097152)     // CAPF u64 keys (byte off %8 == 0)
#define LIST_OFF (KEY_OFF + 8192)       // flagged-query list (ints)
#define CNT_OFF  (LIST_OFF + CAPF)      // atomic counter (int)
#define IDX_OFF  ((size_t)MMM * DDIM)   // output 1: indices as float

typedef short short8v __attribute__((ext_vector_type(8)));
typedef _Float16 half8v __attribute__((ext_vector_type(8)));
typedef float f32x4   __attribute__((ext_vector_type(4)));

__device__ inline unsigned short f2h(float f) {           // fp32 -> fp16 RNE
  _Float16 h = (_Float16)f;                                // v_cvt_f16_f32
  return *(unsigned short*)&h;
}

// async global->LDS, 16B per lane; LDS dest = uniform base + lane*16
__device__ inline void gl_lds16(const short* g, short* l) {
  __builtin_amdgcn_global_load_lds(
      (const __attribute__((address_space(1))) unsigned int*)g,
      (__attribute__((address_space(3))) unsigned int*)l, 16, 0, 0);
}

__device__ inline unsigned mono(float f) {   // monotone float -> uint
  unsigned u = __float_as_uint(f);
  return (u & 0x80000000u) ? ~u : (u | 0x80000000u);
}

// ---- fused: x transpose->fp16 plane  +  embed->fp16 plane / halfe2 / init --
// blocks [0,4096): conv_x work; blocks [4096,4608): conv_e work.
__global__ __launch_bounds__(256)
void conv_xe(const float* __restrict__ x, const float* __restrict__ embed,
             float* __restrict__ halfe2, float* __restrict__ out) {
  __shared__ float xt[64][65];          // +1 pad: conflict-free column reads
  const int t = threadIdx.x;

  if (blockIdx.x >= 4096) {             // ---- embed part (512 blocks) ----
    const int blk = blockIdx.x - 4096;
    const int gid = blk * 256 + t;
    if (gid == 0) *(int*)&out[CNT_OFF] = 0;
    if (gid < CAPF) ((unsigned long long*)&out[KEY_OFF])[gid] = ~0ull;
    const int row  = blk * 4 + (t >> 6);
    const int lane = t & 63;
    const float* e = embed + (size_t)row * DDIM;
    short* eh = (short*)&out[EH_OFF];
    const float4 v0 = *(const float4*)&e[lane*8];
    const float4 v1 = *(const float4*)&e[lane*8 + 4];
    const float vv[8] = {v0.x,v0.y,v0.z,v0.w,v1.x,v1.y,v1.z,v1.w};
    float s = 0.f;
    short8v p;
    #pragma unroll
    for (int i = 0; i < 8; ++i) { s = fmaf(vv[i], vv[i], s); p[i] = (short)f2h(vv[i]); }
    *(short8v*)&eh[(size_t)row * DDIM + lane*8] = p;
    #pragma unroll
    for (int off = 32; off >= 1; off >>= 1) s += __shfl_xor(s, off, 64);
    if (lane == 0) halfe2[row] = 0.5f * s;
    return;
  }

  // ---- x part (4096 blocks): [b][d][n] -> xh[m][d], m = b*4096+n ----
  const int nt = blockIdx.x & 63, dt = (blockIdx.x >> 6) & 7, b = blockIdx.x >> 9;
  const int n0 = nt * 64, d0 = dt * 64;
  const float* xb = x + ((size_t)b * DDIM + d0) * NNN + n0;
  #pragma unroll
  for (int i = 0; i < 4; ++i) {
    const int fid = t + 256*i;
    const int dl = fid >> 4, n4 = (fid & 15) * 4;
    const float4 v = *(const float4*)&xb[(size_t)dl * NNN + n4];
    xt[dl][n4+0] = v.x; xt[dl][n4+1] = v.y; xt[dl][n4+2] = v.z; xt[dl][n4+3] = v.w;
  }
  __syncthreads();
  short* xh = (short*)&out[XH_OFF];
  const int m0 = b * NNN + n0;
  #pragma unroll
  for (int i = 0; i < 2; ++i) {
    const int id = t + 256*i;
    const int m = id >> 3, ch = (id & 7) * 8;
    short8v p;
    #pragma unroll
    for (int j = 0; j < 8; ++j) p[j] = (short)f2h(xt[ch + j][m]);
    *(short8v*)&xh[(size_t)(m0 + m) * DDIM + d0 + ch] = p;
  }
}

// ---- main: triple-buffered counted-vmcnt fp16 MFMA GEMM + deferred argmin --
// score[q][k] = 0.5*||e_k||^2 - <x_q, e_k>   (cross term in fp16, f32 accum)
__global__ __launch_bounds__(256, 2)
void vq_main(const float* __restrict__ halfe2, float* __restrict__ out) {
  __shared__ __align__(16) short lds[NBUF * BUFS];   // 72 KB
  const short* xh = (const short*)&out[XH_OFF];
  const short* eh = (const short*)&out[EH_OFF];

  const int t  = threadIdx.x;
  const int mb = blockIdx.x >> 1, ks = blockIdx.x & 1;
  const int q0 = mb * TMQ;
  const int kbase = ks * KHALF;
  const int w = t >> 6, lane = t & 63;
  const int mw = (w >> 1) * 64, nw = (w & 1) * 128;   // wave 64x128 sub-tile
  const int l15 = lane & 15, lg = lane >> 4;
  const int c0 = w * 6;                                // 6 1-KB chunks per wave
  const int lrow = lane >> 2;                          // row within 16-row chunk
  // physical slot (lane&3) holds logical quad (p - (row>>1)) & 3:
  const int scol = ((((lane & 3) - ((lane >> 3) & 3)) & 3) << 3);

  // deferred per-lane running (best, idx, 2nd-best) for 16 queries/lane
  float rv1[16], rv2[16]; int ri1[16];
  #pragma unroll
  for (int i = 0; i < 16; ++i) { rv1[i] = INFINITY; rv2[i] = INFINITY; ri1[i] = 0x7FFFFFFF; }

  // stage round R (24 KB: 128 q-rows + 256 e-rows x 32 d) into buffer tb
  auto STAGE = [&](int R, int tb) {
    const int kt_ = R >> 4, dr_ = R & 15;
    const int kb_ = kbase + kt_ * TNC;
    const int d0_ = dr_ * BK;
    short* buf = lds + tb * BUFS;
    #pragma unroll
    for (int j = 0; j < 6; ++j) {
      const int c = c0 + j;
      const short* src = (c < 8)
        ? xh + (size_t)(q0 + c*16 + lrow) * DDIM + d0_ + scol
        : eh + (size_t)(kb_ + (c-8)*16 + lrow) * DDIM + d0_ + scol;
      gl_lds16(src, buf + c * 512);
    }
  };

  // prologue: 2-deep fill; wait for buf0 (6 newest = STAGE(1) may stay in flight)
  STAGE(0, 0);
  STAGE(1, 1);
  asm volatile("s_waitcnt vmcnt(6)" ::: "memory");
  __builtin_amdgcn_s_barrier();

  int bi = 0;                                          // buffer holding round R
  for (int kt = 0; kt < NKT; ++kt) {
    const int kb = kbase + kt * TNC;
    f32x4 acc[4][8];
    #pragma unroll
    for (int mi = 0; mi < 4; ++mi)
      #pragma unroll
      for (int ni = 0; ni < 8; ++ni) acc[mi][ni] = (f32x4){0.f,0.f,0.f,0.f};

    for (int dr = 0; dr < NDR; ++dr) {
      const int R = kt * NDR + dr;
      const int nb = bi ? bi - 1 : 2;                  // (bi+2)%3
      if (R + 2 < TOTR) STAGE(R + 2, nb);              // 2-round-deep prefetch
      const short* xs = lds + bi * BUFS;
      const short* es = xs + TMQ * BK;
      half8v bfr[8];
      #pragma unroll
      for (int ni = 0; ni < 8; ++ni) {
        const int row = nw + ni*16 + l15;
        bfr[ni] = *(const half8v*)&es[row*32 + (((lg + (row >> 1)) & 3) << 3)];
      }
      #pragma unroll
      for (int mi = 0; mi < 4; ++mi) {
        const int row = mw + mi*16 + l15;
        const half8v a = *(const half8v*)&xs[row*32 + (((lg + (row >> 1)) & 3) << 3)];
        #pragma unroll
        for (int ni = 0; ni < 8; ++ni)
          acc[mi][ni] = __builtin_amdgcn_mfma_f32_16x16x32_f16(a, bfr[ni], acc[mi][ni], 0,0,0);
      }
      // counted wait: all but the newest 6 loads (STAGE(R+2)) must have landed
      if (R + 2 < TOTR) { asm volatile("s_waitcnt vmcnt(6)" ::: "memory"); }
      else              { asm volatile("s_waitcnt vmcnt(0)" ::: "memory"); }
      __builtin_amdgcn_s_barrier();
      bi = (bi == 2) ? 0 : bi + 1;
    }

    // per-k-tile: per-lane tournament only (no cross-lane traffic);
    // candidate indices strictly ascend -> strict < keeps first index
    float he[8];
    #pragma unroll
    for (int ni = 0; ni < 8; ++ni) he[ni] = halfe2[kb + nw + ni*16 + l15];
    #pragma unroll
    for (int mi = 0; mi < 4; ++mi) {
      #pragma unroll
      for (int r = 0; r < 4; ++r) {
        const int e_ = mi*4 + r;
        #pragma unroll
        for (int ni = 0; ni < 8; ++ni) {
          const float sc = he[ni] - acc[mi][ni][r];
          if (sc < rv1[e_]) { rv2[e_] = rv1[e_]; rv1[e_] = sc; ri1[e_] = kb + nw + ni*16 + l15; }
          else rv2[e_] = fminf(rv2[e_], sc);
        }
      }
    }
  }

  // once: cross-lane merge over the 16 code-columns (within each 16-lane group)
  #pragma unroll
  for (int e_ = 0; e_ < 16; ++e_) {
    float v1 = rv1[e_], v2 = rv2[e_]; int i1 = ri1[e_];
    #pragma unroll
    for (int off = 1; off < 16; off <<= 1) {
      const float ov1 = __shfl_xor(v1, off, 64);
      const int   oi1 = __shfl_xor(i1, off, 64);
      const float ov2 = __shfl_xor(v2, off, 64);
      if (ov1 < v1 || (ov1 == v1 && oi1 < i1)) { v2 = fminf(v1, ov2); v1 = ov1; i1 = oi1; }
      else v2 = fminf(v2, ov1);
    }
    rv1[e_] = v1; rv2[e_] = v2; ri1[e_] = i1;
  }

  // merge the two code-half waves (w&1) per query via LDS; store partial triple
  __syncthreads();
  float* mbuf = (float*)lds;   // [128 q][2 halves][3]
  if (l15 == 0) {
    #pragma unroll
    for (int mi = 0; mi < 4; ++mi)
      #pragma unroll
      for (int r = 0; r < 4; ++r) {
        const int ql = mw + mi*16 + lg*4 + r;
        const int slot = (ql*2 + (w & 1))*3;
        const int e_ = mi*4 + r;
        mbuf[slot+0] = rv1[e_];
        mbuf[slot+1] = __int_as_float(ri1[e_]);
        mbuf[slot+2] = rv2[e_];
      }
  }
  __syncthreads();
  if (t < TMQ) {
    const float a1 = mbuf[t*6+0]; const int ai = __float_as_int(mbuf[t*6+1]); const float a2 = mbuf[t*6+2];
    const float b1 = mbuf[t*6+3]; const int bi2 = __float_as_int(mbuf[t*6+4]); const float b2 = mbuf[t*6+5];
    float v1, v2; int i1;
    if (b1 < a1 || (b1 == a1 && bi2 < ai)) { v1 = b1; i1 = bi2; v2 = fminf(a1, b2); }
    else                                   { v1 = a1; i1 = ai;  v2 = fminf(a2, b1); }
    f32x4 st = {v1, (float)i1, v2, 0.f};
    *(f32x4*)&out[PART_OFF + ((size_t)(q0 + t)*KSPLIT + ks)*4] = st;
  }
}

// ---- merge K-split partials; write index; flag + inline prep (fused) -------
__global__ void vq_merge(const float* __restrict__ x, float* __restrict__ out) {
  const int q = blockIdx.x * 256 + threadIdx.x;
  float v1, v2; int i1;
  {
    const f32x4 p = *(const f32x4*)&out[PART_OFF + (size_t)q*(KSPLIT*4)];
    v1 = p[0]; i1 = (int)p[1]; v2 = p[2];
  }
  #pragma unroll
  for (int s = 1; s < KSPLIT; ++s) {
    const f32x4 p = *(const f32x4*)&out[PART_OFF + (size_t)q*(KSPLIT*4) + s*4];
    const float b1 = p[0]; const int bi = (int)p[1]; const float b2 = p[2];
    if (b1 < v1 || (b1 == v1 && bi < i1)) { v2 = fminf(v1, b2); v1 = b1; i1 = bi; }
    else v2 = fminf(v2, b1);
  }
  out[IDX_OFF + q] = (float)i1;
  int pos = -1;
  if (v2 - v1 < TAU) {
    pos = atomicAdd((int*)&out[CNT_OFF], 1);
    if (pos < CAPF) ((int*)&out[LIST_OFF])[pos] = q;
    else pos = -1;
  }
  // cooperative whole-wave copy of each flagged row into XF (replaces vq_prep)
  unsigned long long mask = __ballot(pos >= 0);
  const int lane = threadIdx.x & 63;
  float* XF = &out[XF_OFF];
  while (mask) {
    const int src = __ffsll(mask) - 1;
    mask &= mask - 1;
    const int qq = __shfl(q,   src, 64);
    const int pp = __shfl(pos, src, 64);
    const int bb = qq >> 12, nn = qq & (NNN - 1);
    const float* xb = x + (size_t)bb * DDIM * NNN + nn;
    #pragma unroll
    for (int j = 0; j < 8; ++j) {
      const int d = lane + 64*j;
      XF[(size_t)pp * DDIM + d] = xb[(size_t)d * NNN];
    }
  }
}

// ---- refine: exact fp32 microtile GEMM over flagged slots ------------------
__global__ __launch_bounds__(256, 2)
void vq_refine(const float* __restrict__ embed, const float* __restrict__ halfe2,
               float* __restrict__ out) {
  const int nf0 = *(const int*)&out[CNT_OFF];
  const int nf  = nf0 < CAPF ? nf0 : CAPF;
  const int s0  = blockIdx.y * 64;
  if (s0 >= nf) return;
  __shared__ float xs[32][68];   // stride 68: float4-aligned, <=4-way stage writes
  __shared__ float es[32][132];
  const int t = threadIdx.x, tx = t & 15, ty = t >> 4;
  const int kb = blockIdx.x * 128;
  const float* XF = &out[XF_OFF];
  unsigned long long* keys = (unsigned long long*)&out[KEY_OFF];

  float acc[4][8];
  #pragma unroll
  for (int i = 0; i < 4; ++i)
    #pragma unroll
    for (int j = 0; j < 8; ++j) acc[i][j] = 0.f;

  for (int dc = 0; dc < 16; ++dc) {
    __syncthreads();
    #pragma unroll
    for (int i = 0; i < 2; ++i) {        // xs[d][m] <- XF[s0+m][.] row float4 reads
      const int l = t + 256*i;           // 512 float4
      const int m = l >> 3, f = l & 7;
      const float4 v = *(const float4*)&XF[(size_t)(s0 + m) * DDIM + dc*32 + 4*f];
      xs[4*f+0][m] = v.x; xs[4*f+1][m] = v.y; xs[4*f+2][m] = v.z; xs[4*f+3][m] = v.w;
    }
    #pragma unroll
    for (int i = 0; i < 4; ++i) {        // es[d][k] <- embed rows (float4)
      const int l = t + 256*i;
      const int k = l >> 3, f = l & 7;
      const float4 v = *(const float4*)&embed[(size_t)(kb + k)*DDIM + dc*32 + 4*f];
      es[4*f+0][k] = v.x; es[4*f+1][k] = v.y; es[4*f+2][k] = v.z; es[4*f+3][k] = v.w;
    }
    __syncthreads();
    #pragma unroll
    for (int d = 0; d < 32; ++d) {       // sequential d: deterministic sum order
      const float4 a4 = *(const float4*)&xs[d][ty*4];
      const float4 b0 = *(const float4*)&es[d][tx*4];
      const float4 b1 = *(const float4*)&es[d][64 + tx*4];
      const float a[4]  = {a4.x, a4.y, a4.z, a4.w};
      const float bb[8] = {b0.x, b0.y, b0.z, b0.w, b1.x, b1.y, b1.z, b1.w};
      #pragma unroll
      for (int i = 0; i < 4; ++i)
        #pragma unroll
        for (int j = 0; j < 8; ++j)
          acc[i][j] = fmaf(a[i], bb[j], acc[i][j]);
    }
  }

  const int kb0 = kb + tx*4, kb1 = kb + 64 + tx*4;
  const float4 h0 = *(const float4*)&halfe2[kb0];
  const float4 h1 = *(const float4*)&halfe2[kb1];
  const float hh[8] = {h0.x, h0.y, h0.z, h0.w, h1.x, h1.y, h1.z, h1.w};
  #pragma unroll
  for (int i = 0; i < 4; ++i) {
    float v = hh[0] - acc[i][0];
    int  vi = kb0;
    #pragma unroll
    for (int j = 1; j < 8; ++j) {
      const float w  = hh[j] - acc[i][j];
      const int   wk = (j < 4) ? (kb0 + j) : (kb1 + j - 4);
      if (w < v) { v = w; vi = wk; }     // ascending codes: strict < keeps first
    }
    #pragma unroll
    for (int off = 1; off < 16; off <<= 1) {
      const float ov = __shfl_xor(v, off, 64);
      const int   oi = __shfl_xor(vi, off, 64);
      if (ov < v || (ov == v && oi < vi)) { v = ov; vi = oi; }
    }
    if (tx == 0) {
      const unsigned long long key =
          ((unsigned long long)mono(v) << 32) | (unsigned)vi;
      atomicMin(&keys[s0 + ty*4 + i], key);
    }
  }
}

// ---- apply: decode refined keys back into IDX ------------------------------
__global__ void vq_apply(float* __restrict__ out) {
  const int slot = blockIdx.x * 256 + threadIdx.x;
  const int nf0 = *(const int*)&out[CNT_OFF];
  const int nf  = nf0 < CAPF ? nf0 : CAPF;
  if (slot >= nf) return;
  const int q = ((const int*)&out[LIST_OFF])[slot];
  const unsigned long long k = ((const unsigned long long*)&out[KEY_OFF])[slot];
  if (k != ~0ull) out[IDX_OFF + q] = (float)(unsigned)(k & 0xFFFFFFFFull);
}

// ---- gather: LDS-staged embed rows, zero scattered VMEM --------------------
// 1024 blocks x 32 queries. Stage the 32 selected embed rows via coalesced
// 1-KB float4 reads (embed L2-resident), then write output transposed from
// LDS ([32][516]: float4-aligned staging writes, ~4-way column reads).
__global__ __launch_bounds__(256)
void vq_gather(const float* __restrict__ embed, float* __restrict__ out) {
  __shared__ float ls[32][516];
  __shared__ int idx_s[32];
  const int t  = threadIdx.x;
  const int q0 = blockIdx.x * 32;
  const int b  = q0 >> 12, n0 = q0 & (NNN-1);
  if (t < 32) idx_s[t] = (int)out[IDX_OFF + q0 + t];
  __syncthreads();
  {
    const int rh  = t >> 7;            // 2 rows per pass, 128 threads per row
    const int col = (t & 127) * 4;
    #pragma unroll
    for (int p = 0; p < 16; ++p) {
      const int r = p*2 + rh;
      const float4 v = *(const float4*)&embed[(size_t)idx_s[r]*DDIM + col];
      *(float4*)&ls[r][col] = v;
    }
  }
  __syncthreads();
  float* qb = out + (size_t)b * DDIM * NNN + n0;
  #pragma unroll
  for (int j = 0; j < 16; ++j) {
    const int d  = 32*j + (t >> 3);
    const int n4 = (t & 7) * 4;
    float4 v;
    v.x = ls[n4+0][d]; v.y = ls[n4+1][d]; v.z = ls[n4+2][d]; v.w = ls[n4+3][d];
    *(float4*)&qb[(size_t)d * NNN + n4] = v;
  }
}

extern "C" void kernel_launch(void* const* d_in, const int* in_sizes, int n_in,
                              void* d_out, int out_size, void* d_ws, size_t ws_size,
                              hipStream_t stream) {
  const float* x     = (const float*)d_in[0];   // [8, 512, 4096] fp32
  const float* embed = (const float*)d_in[1];   // [2048, 512] fp32
  float* out    = (float*)d_out;
  float* halfe2 = (float*)d_ws;                 // 8 KB scratch

  hipLaunchKernelGGL(conv_xe, dim3(4096 + KKK/4), dim3(256), 0, stream, x, embed, halfe2, out);
  hipLaunchKernelGGL(vq_main,  dim3((MMM/TMQ)*KSPLIT), dim3(256), 0, stream, halfe2, out);
  hipLaunchKernelGGL(vq_merge, dim3(MMM/256), dim3(256), 0, stream, x, out);
  hipLaunchKernelGGL(vq_refine,dim3(16, CAPF/64), dim3(256), 0, stream, embed, halfe2, out);
  hipLaunchKernelGGL(vq_apply, dim3(CAPF/256),dim3(256), 0, stream, out);
  hipLaunchKernelGGL(vq_gather,dim3(MMM/32),  dim3(256), 0, stream, embed, out);
}